// Round 1
// baseline (36235.336 us; speedup 1.0000x reference)
//
#include <hip/hip_runtime.h>

// MultiLayerRNN: B=128, T=1024, D_IN=256, H=512, C=1000
// Strategy:
//   prep    : weights -> bf16 device globals, fold biases, zero h state/barrier
//   pre0    : pre0[t][b][n] = x[b,t,:]@Wx0^T + Wx0_b + Wh0_b  (parallel MFMA GEMM)
//   rnn     : persistent kernel, 160 WGs, software-pipelined 2-layer recurrence,
//             spin barrier (agent-scope atomics), weights in LDS (XOR-swizzled)
//   fc      : h1_final @ fc_w^T + fc_b -> d_out (fp32)

#define NWG_RNN 160u

typedef __attribute__((ext_vector_type(8))) short bf16x8_t;
typedef __attribute__((ext_vector_type(4))) float f32x4;

__device__ __align__(16) unsigned short g_Wh0[512 * 512];       // bf16 [n][k]
__device__ __align__(16) unsigned short g_W1[512 * 1024];       // bf16 [n][1024] = [Wx1 | Wh1]
__device__ float g_b1[512];
__device__ __align__(16) unsigned short g_pre0[1024 * 128 * 512]; // bf16 [t][b][n]
__device__ __align__(16) unsigned short g_h0[2][128 * 512];     // bf16 ring
__device__ __align__(16) unsigned short g_h1[2][128 * 512];     // bf16 ring
__device__ unsigned g_count;

__device__ __forceinline__ unsigned short f2bf(float f) {
  unsigned u = __float_as_uint(f);
  u += 0x7fffu + ((u >> 16) & 1u);   // RNE
  return (unsigned short)(u >> 16);
}
__device__ __forceinline__ float bf2f(unsigned short h) {
  return __uint_as_float(((unsigned)h) << 16);
}
__device__ __forceinline__ bf16x8_t cvt8f(const float* p) {
  bf16x8_t r;
#pragma unroll
  for (int i = 0; i < 8; ++i) r[i] = (short)f2bf(p[i]);
  return r;
}
__device__ __forceinline__ float tanh_fast(float x) {
  float e = __expf(2.f * x);
  return 1.f - 2.f / (e + 1.f);      // exact at +/-inf
}

// ---------------------------------------------------------------- prep
__global__ void prep_kernel(const float* __restrict__ Wh0_w, const float* __restrict__ Wx1_w,
                            const float* __restrict__ Wh1_w, const float* __restrict__ Wx1_b,
                            const float* __restrict__ Wh1_b) {
  unsigned tid = blockIdx.x * blockDim.x + threadIdx.x;
  unsigned stride = gridDim.x * blockDim.x;
  for (unsigned i = tid; i < 512u * 512u; i += stride) g_Wh0[i] = f2bf(Wh0_w[i]);
  for (unsigned i = tid; i < 512u * 1024u; i += stride) {
    unsigned n = i >> 10, k = i & 1023u;
    float v = (k < 512u) ? Wx1_w[n * 512u + k] : Wh1_w[n * 512u + k - 512u];
    g_W1[i] = f2bf(v);
  }
  for (unsigned i = tid; i < 512u; i += stride) g_b1[i] = Wx1_b[i] + Wh1_b[i];
  unsigned short* h0p = &g_h0[0][0];
  unsigned short* h1p = &g_h1[0][0];
  for (unsigned i = tid; i < 2u * 128u * 512u; i += stride) { h0p[i] = 0; h1p[i] = 0; }
  if (tid == 0) g_count = 0u;
}

// ---------------------------------------------------------------- pre0: x @ Wx0^T + biases
__global__ __launch_bounds__(512) void pre0_kernel(const float* __restrict__ x,
                                                   const float* __restrict__ Wx0_w,
                                                   const float* __restrict__ Wx0_b,
                                                   const float* __restrict__ Wh0_b) {
  const unsigned t = blockIdx.x;                 // one t per WG, out tile [128][512]
  const unsigned lane = threadIdx.x & 63u, w = threadIdx.x >> 6;  // 8 waves
  const unsigned lrow = lane & 15u, lko = (lane >> 4) * 8u, crow = (lane >> 4) * 4u;
  const unsigned ncol0 = w * 64u;                // wave owns 64 n-cols
  f32x4 z4 = {0.f, 0.f, 0.f, 0.f};
  f32x4 acc[8][4];
#pragma unroll
  for (int a = 0; a < 8; ++a)
#pragma unroll
    for (int b = 0; b < 4; ++b) acc[a][b] = z4;

  for (unsigned kk = 0; kk < 8u; ++kk) {         // K = 256
    unsigned k0 = kk * 32u + lko;
    bf16x8_t bfr[4];
#pragma unroll
    for (unsigned nj = 0; nj < 4u; ++nj) {
      unsigned n = ncol0 + nj * 16u + lrow;
      bfr[nj] = cvt8f(Wx0_w + n * 256u + k0);
    }
#pragma unroll
    for (unsigned mi = 0; mi < 8u; ++mi) {
      unsigned m = mi * 16u + lrow;
      bf16x8_t afr = cvt8f(x + ((size_t)m * 1024u + t) * 256u + k0);
#pragma unroll
      for (unsigned nj = 0; nj < 4u; ++nj)
        acc[mi][nj] = __builtin_amdgcn_mfma_f32_16x16x32_bf16(afr, bfr[nj], acc[mi][nj], 0, 0, 0);
    }
  }
#pragma unroll
  for (unsigned mi = 0; mi < 8u; ++mi)
#pragma unroll
    for (unsigned nj = 0; nj < 4u; ++nj)
#pragma unroll
      for (unsigned r = 0; r < 4u; ++r) {
        unsigned row = mi * 16u + crow + r;
        unsigned col = ncol0 + nj * 16u + lrow;
        float v = acc[mi][nj][r] + Wx0_b[col] + Wh0_b[col];
        g_pre0[((size_t)t * 128u + row) * 512u + col] = f2bf(v);
      }
}

// ---------------------------------------------------------------- persistent recurrence
__global__ __launch_bounds__(256) void rnn_kernel() {
  const unsigned wg = blockIdx.x;
  const unsigned tid = threadIdx.x;
  const unsigned lane = tid & 63u, w = tid >> 6;
  const unsigned lrow = lane & 15u, lko = (lane >> 4) * 8u, crow = (lane >> 4) * 4u;
  __shared__ __align__(16) unsigned char smem[65536];   // [0,32K) = B slice, [32K,64K) = 4 wave red bufs
  float* redbase = (float*)(smem + 32768);
  const bool is0 = (wg < 32u);
  unsigned rbase, cbase;
  if (is0) { rbase = (wg >> 4) * 64u;  cbase = (wg & 15u) * 32u; }   // layer0: 64r x 32c
  else { unsigned wgl = wg - 32u; rbase = (wgl >> 5) * 32u; cbase = (wgl & 31u) * 16u; } // layer1: 32r x 16c

  // stage weight slice into LDS once, XOR-swizzled (row stride 1024B/2048B -> bank conflict otherwise)
  if (is0) {
    for (unsigned idx = tid; idx < 32u * 64u; idx += 256u) {
      unsigned row = idx >> 6, ko = idx & 63u;
      uint4 v = *(const uint4*)(g_Wh0 + (cbase + row) * 512u + ko * 8u);
      *(uint4*)(smem + row * 1024u + ((ko * 16u) ^ ((row & 7u) << 4))) = v;
    }
  } else {
    for (unsigned idx = tid; idx < 16u * 128u; idx += 256u) {
      unsigned row = idx >> 7, ko = idx & 127u;
      uint4 v = *(const uint4*)(g_W1 + (cbase + row) * 1024u + ko * 8u);
      *(uint4*)(smem + row * 2048u + ((ko * 16u) ^ ((row & 7u) << 4))) = v;
    }
  }
  __syncthreads();

  f32x4 z4 = {0.f, 0.f, 0.f, 0.f};

  for (unsigned i = 0; i <= 1024u; ++i) {
    if (is0) {
      if (i < 1024u) {                            // layer0 step t = i
        const unsigned t = i;
        const unsigned short* __restrict__ Ap = g_h0[(t + 1u) & 1u];  // slot(t-1)
        f32x4 acc[4][2];
#pragma unroll
        for (int a = 0; a < 4; ++a) { acc[a][0] = z4; acc[a][1] = z4; }
        const unsigned kb = w * 128u;             // wave K-slice of 512
        for (unsigned kk = 0; kk < 4u; ++kk) {
          unsigned k0 = kb + kk * 32u + lko;
          bf16x8_t bfr[2];
#pragma unroll
          for (unsigned nj = 0; nj < 2u; ++nj) {
            unsigned nl = nj * 16u + lrow;
            bfr[nj] = *(const bf16x8_t*)(smem + nl * 1024u + ((2u * k0) ^ ((nl & 7u) << 4)));
          }
#pragma unroll
          for (unsigned mi = 0; mi < 4u; ++mi) {
            unsigned m = rbase + mi * 16u + lrow;
            bf16x8_t afr = *(const bf16x8_t*)(Ap + m * 512u + k0);
#pragma unroll
            for (unsigned nj = 0; nj < 2u; ++nj)
              acc[mi][nj] = __builtin_amdgcn_mfma_f32_16x16x32_bf16(afr, bfr[nj], acc[mi][nj], 0, 0, 0);
          }
        }
        float* redw = redbase + w * 2048u;        // [64][32] f32 per wave
#pragma unroll
        for (unsigned mi = 0; mi < 4u; ++mi)
#pragma unroll
          for (unsigned nj = 0; nj < 2u; ++nj)
#pragma unroll
            for (unsigned r = 0; r < 4u; ++r)
              redw[(mi * 16u + crow + r) * 32u + nj * 16u + lrow] = acc[mi][nj][r];
        __syncthreads();
        unsigned c = tid & 31u, r0 = (tid >> 5) * 8u;
#pragma unroll
        for (unsigned rr = 0; rr < 8u; ++rr) {
          unsigned r = r0 + rr;
          unsigned off = r * 32u + c;
          float s = redbase[off] + redbase[2048u + off] + redbase[4096u + off] + redbase[6144u + off];
          float v = s + bf2f(g_pre0[((size_t)t * 128u + rbase + r) * 512u + cbase + c]);
          g_h0[t & 1u][(rbase + r) * 512u + cbase + c] = f2bf(tanh_fast(v));
        }
      }
    } else {
      if (i >= 1u) {                              // layer1 step t1 = i-1 (pipelined)
        const unsigned t1 = i - 1u;
        const unsigned short* __restrict__ Ap = (w < 2u) ? g_h0[t1 & 1u] : g_h1[(t1 + 1u) & 1u];
        const unsigned koff = (w < 2u) ? w * 256u : (w - 2u) * 256u;  // k within source
        const unsigned kb = w * 256u;                                  // k within B (LDS)
        f32x4 acc[2];
        acc[0] = z4; acc[1] = z4;
        for (unsigned kk = 0; kk < 8u; ++kk) {
          unsigned kl = koff + kk * 32u + lko;
          unsigned kg = kb + kk * 32u + lko;
          bf16x8_t bfr = *(const bf16x8_t*)(smem + lrow * 2048u + ((2u * kg) ^ ((lrow & 7u) << 4)));
#pragma unroll
          for (unsigned mi = 0; mi < 2u; ++mi) {
            unsigned m = rbase + mi * 16u + lrow;
            bf16x8_t afr = *(const bf16x8_t*)(Ap + m * 512u + kl);
            acc[mi] = __builtin_amdgcn_mfma_f32_16x16x32_bf16(afr, bfr, acc[mi], 0, 0, 0);
          }
        }
        float* redw = redbase + w * 512u;         // [32][16] f32 per wave
#pragma unroll
        for (unsigned mi = 0; mi < 2u; ++mi)
#pragma unroll
          for (unsigned r = 0; r < 4u; ++r)
            redw[(mi * 16u + crow + r) * 16u + lrow] = acc[mi][r];
        __syncthreads();
        for (unsigned idx = tid; idx < 512u; idx += 256u) {
          unsigned r = idx >> 4, cc = idx & 15u;
          float s = redbase[idx] + redbase[512u + idx] + redbase[1024u + idx] + redbase[1536u + idx];
          float v = s + g_b1[cbase + cc];
          g_h1[t1 & 1u][(rbase + r) * 512u + cbase + cc] = f2bf(tanh_fast(v));
        }
      }
    }
    // ---- grid-wide spin barrier (all 160 WGs co-resident) ----
    __threadfence();            // each thread flushes its stores to agent scope
    __syncthreads();
    if (tid == 0u) {
      __hip_atomic_fetch_add(&g_count, 1u, __ATOMIC_ACQ_REL, __HIP_MEMORY_SCOPE_AGENT);
      unsigned target = (i + 1u) * NWG_RNN;
      while (__hip_atomic_load(&g_count, __ATOMIC_ACQUIRE, __HIP_MEMORY_SCOPE_AGENT) < target) {}
    }
    __syncthreads();
    __threadfence();            // acquire side: invalidate caches before reading fresh h
  }
}

// ---------------------------------------------------------------- fc: h1_final @ fc_w^T + fc_b
__global__ __launch_bounds__(256) void fc_kernel(const float* __restrict__ fc_w,
                                                 const float* __restrict__ fc_b,
                                                 float* __restrict__ out) {
  const unsigned wg = blockIdx.x;                 // 16 WGs x 64 cols
  const unsigned lane = threadIdx.x & 63u, w = threadIdx.x >> 6;
  const unsigned lrow = lane & 15u, lko = (lane >> 4) * 8u, crow = (lane >> 4) * 4u;
  const unsigned n0 = wg * 64u + w * 16u;
  const unsigned short* __restrict__ h1 = g_h1[1];  // slot(1023)
  f32x4 z4 = {0.f, 0.f, 0.f, 0.f};
  f32x4 acc[8];
#pragma unroll
  for (int a = 0; a < 8; ++a) acc[a] = z4;
  const unsigned n = n0 + lrow;
  for (unsigned kk = 0; kk < 16u; ++kk) {         // K = 512
    unsigned k0 = kk * 32u + lko;
    bf16x8_t bfr = {0, 0, 0, 0, 0, 0, 0, 0};
    if (n < 1000u) bfr = cvt8f(fc_w + n * 512u + k0);
#pragma unroll
    for (unsigned mi = 0; mi < 8u; ++mi) {
      bf16x8_t afr = *(const bf16x8_t*)(h1 + (mi * 16u + lrow) * 512u + k0);
      acc[mi] = __builtin_amdgcn_mfma_f32_16x16x32_bf16(afr, bfr, acc[mi], 0, 0, 0);
    }
  }
#pragma unroll
  for (unsigned mi = 0; mi < 8u; ++mi)
#pragma unroll
    for (unsigned r = 0; r < 4u; ++r) {
      unsigned row = mi * 16u + crow + r;
      unsigned col = n0 + lrow;
      if (col < 1000u) out[row * 1000u + col] = acc[mi][r] + fc_b[col];
    }
}

// ---------------------------------------------------------------- launch
extern "C" void kernel_launch(void* const* d_in, const int* in_sizes, int n_in,
                              void* d_out, int out_size, void* d_ws, size_t ws_size,
                              hipStream_t stream) {
  (void)in_sizes; (void)n_in; (void)out_size; (void)d_ws; (void)ws_size;
  const float* x     = (const float*)d_in[0];
  const float* Wx0_w = (const float*)d_in[1];
  const float* Wx0_b = (const float*)d_in[2];
  const float* Wh0_w = (const float*)d_in[3];
  const float* Wh0_b = (const float*)d_in[4];
  const float* Wx1_w = (const float*)d_in[5];
  const float* Wx1_b = (const float*)d_in[6];
  const float* Wh1_w = (const float*)d_in[7];
  const float* Wh1_b = (const float*)d_in[8];
  const float* fc_w  = (const float*)d_in[9];
  const float* fc_b  = (const float*)d_in[10];

  prep_kernel<<<1024, 256, 0, stream>>>(Wh0_w, Wx1_w, Wh1_w, Wx1_b, Wh1_b);
  pre0_kernel<<<1024, 512, 0, stream>>>(x, Wx0_w, Wx0_b, Wh0_b);
  rnn_kernel<<<NWG_RNN, 256, 0, stream>>>();
  fc_kernel<<<16, 256, 0, stream>>>(fc_w, fc_b, (float*)d_out);
}

// Round 2
// 19298.723 us; speedup vs baseline: 1.8776x; 1.8776x over previous
//
#include <hip/hip_runtime.h>

// MultiLayerRNN: B=128, T=1024, D_IN=256, H=512, C=1000
// Round 2: fabric-quiet persistent RNN.
//   - h state exchanged through Infinity Cache via RELAXED agent-scope atomics
//     (no buffer_wbl2/buffer_inv cache ops in the hot loop at all)
//   - all-to-all flag barrier: 1 relaxed store + parallel relaxed polls
//   - 48 WGs: 16 layer0 (128r x 32c, waves M-split) + 32 layer1 (128r x 16c)

#define NWG 48u
#define NWG0 16u

typedef __attribute__((ext_vector_type(8))) short bf16x8_t;
typedef __attribute__((ext_vector_type(4))) float f32x4;

__device__ __align__(16) unsigned short g_Wh0[512 * 512];        // bf16 [n][k]
__device__ __align__(16) unsigned short g_W1[512 * 1024];        // bf16 [n][1024] = [Wx1 | Wh1]
__device__ float g_b1[512];
__device__ __align__(16) unsigned short g_pre0[1024 * 128 * 512]; // bf16 [t][b][n]
__device__ unsigned long long g_h0u[2][16384];                    // bf16x4 ring, IC-coherent
__device__ unsigned long long g_h1u[2][16384];
__device__ unsigned g_flag[64];

__device__ __forceinline__ unsigned short f2bf(float f) {
  unsigned u = __float_as_uint(f);
  u += 0x7fffu + ((u >> 16) & 1u);   // RNE
  return (unsigned short)(u >> 16);
}
__device__ __forceinline__ float bf2f(unsigned short h) {
  return __uint_as_float(((unsigned)h) << 16);
}
__device__ __forceinline__ bf16x8_t cvt8f(const float* p) {
  bf16x8_t r;
#pragma unroll
  for (int i = 0; i < 8; ++i) r[i] = (short)f2bf(p[i]);
  return r;
}
__device__ __forceinline__ float tanh_fast(float x) {
  float e = __expf(2.f * x);
  return 1.f - 2.f / (e + 1.f);
}
// 16B of h via two relaxed agent-scope 8B loads (sc0/sc1 -> reads coherent IC, no cache ops)
__device__ __forceinline__ bf16x8_t ld_a16(const unsigned long long* p) {
  union { unsigned long long u[2]; bf16x8_t v; } t;
  t.u[0] = __hip_atomic_load((unsigned long long*)p, __ATOMIC_RELAXED, __HIP_MEMORY_SCOPE_AGENT);
  t.u[1] = __hip_atomic_load((unsigned long long*)(p + 1), __ATOMIC_RELAXED, __HIP_MEMORY_SCOPE_AGENT);
  return t.v;
}
__device__ __forceinline__ void st_a8(unsigned long long* p, unsigned long long v) {
  __hip_atomic_store(p, v, __ATOMIC_RELAXED, __HIP_MEMORY_SCOPE_AGENT);
}

// ---------------------------------------------------------------- prep
__global__ void prep_kernel(const float* __restrict__ Wh0_w, const float* __restrict__ Wx1_w,
                            const float* __restrict__ Wh1_w, const float* __restrict__ Wx1_b,
                            const float* __restrict__ Wh1_b) {
  unsigned tid = blockIdx.x * blockDim.x + threadIdx.x;
  unsigned stride = gridDim.x * blockDim.x;
  for (unsigned i = tid; i < 512u * 512u; i += stride) g_Wh0[i] = f2bf(Wh0_w[i]);
  for (unsigned i = tid; i < 512u * 1024u; i += stride) {
    unsigned n = i >> 10, k = i & 1023u;
    float v = (k < 512u) ? Wx1_w[n * 512u + k] : Wh1_w[n * 512u + k - 512u];
    g_W1[i] = f2bf(v);
  }
  for (unsigned i = tid; i < 512u; i += stride) g_b1[i] = Wx1_b[i] + Wh1_b[i];
  unsigned long long* h0p = &g_h0u[0][0];
  unsigned long long* h1p = &g_h1u[0][0];
  for (unsigned i = tid; i < 2u * 16384u; i += stride) { h0p[i] = 0ull; h1p[i] = 0ull; }
  for (unsigned i = tid; i < 64u; i += stride) g_flag[i] = 0u;
}

// ---------------------------------------------------------------- pre0: x @ Wx0^T + biases
__global__ __launch_bounds__(512) void pre0_kernel(const float* __restrict__ x,
                                                   const float* __restrict__ Wx0_w,
                                                   const float* __restrict__ Wx0_b,
                                                   const float* __restrict__ Wh0_b) {
  const unsigned t = blockIdx.x;
  const unsigned lane = threadIdx.x & 63u, w = threadIdx.x >> 6;
  const unsigned lrow = lane & 15u, lko = (lane >> 4) * 8u, crow = (lane >> 4) * 4u;
  const unsigned ncol0 = w * 64u;
  f32x4 z4 = {0.f, 0.f, 0.f, 0.f};
  f32x4 acc[8][4];
#pragma unroll
  for (int a = 0; a < 8; ++a)
#pragma unroll
    for (int b = 0; b < 4; ++b) acc[a][b] = z4;

  for (unsigned kk = 0; kk < 8u; ++kk) {
    unsigned k0 = kk * 32u + lko;
    bf16x8_t bfr[4];
#pragma unroll
    for (unsigned nj = 0; nj < 4u; ++nj) {
      unsigned n = ncol0 + nj * 16u + lrow;
      bfr[nj] = cvt8f(Wx0_w + n * 256u + k0);
    }
#pragma unroll
    for (unsigned mi = 0; mi < 8u; ++mi) {
      unsigned m = mi * 16u + lrow;
      bf16x8_t afr = cvt8f(x + ((size_t)m * 1024u + t) * 256u + k0);
#pragma unroll
      for (unsigned nj = 0; nj < 4u; ++nj)
        acc[mi][nj] = __builtin_amdgcn_mfma_f32_16x16x32_bf16(afr, bfr[nj], acc[mi][nj], 0, 0, 0);
    }
  }
#pragma unroll
  for (unsigned mi = 0; mi < 8u; ++mi)
#pragma unroll
    for (unsigned nj = 0; nj < 4u; ++nj)
#pragma unroll
      for (unsigned r = 0; r < 4u; ++r) {
        unsigned row = mi * 16u + crow + r;
        unsigned col = ncol0 + nj * 16u + lrow;
        float v = acc[mi][nj][r] + Wx0_b[col] + Wh0_b[col];
        g_pre0[((size_t)t * 128u + row) * 512u + col] = f2bf(v);
      }
}

// ---------------------------------------------------------------- persistent recurrence
__global__ __launch_bounds__(256) void rnn_kernel() {
  const unsigned wg = blockIdx.x;
  const unsigned tid = threadIdx.x;
  const unsigned lane = tid & 63u, w = tid >> 6;
  const unsigned lrow = lane & 15u, lko = (lane >> 4) * 8u, crow = (lane >> 4) * 4u;
  __shared__ __align__(16) unsigned char smem[49152];     // 32KB weights + 16KB f32 stage
  float* stage = (float*)(smem + 32768);
  const bool is0 = (wg < NWG0);
  const unsigned cbase = is0 ? (wg * 32u) : ((wg - NWG0) * 16u);

  // stage weight slice into LDS once, XOR-swizzled
  if (is0) {
    for (unsigned idx = tid; idx < 32u * 64u; idx += 256u) {
      unsigned row = idx >> 6, ko = idx & 63u;
      uint4 v = *(const uint4*)(g_Wh0 + (cbase + row) * 512u + ko * 8u);
      *(uint4*)(smem + row * 1024u + ((ko * 16u) ^ ((row & 7u) << 4))) = v;
    }
  } else {
    for (unsigned idx = tid; idx < 16u * 128u; idx += 256u) {
      unsigned row = idx >> 7, ko = idx & 127u;
      uint4 v = *(const uint4*)(g_W1 + (cbase + row) * 1024u + ko * 8u);
      *(uint4*)(smem + row * 2048u + ((ko * 16u) ^ ((row & 7u) << 4))) = v;
    }
  }
  __syncthreads();

  const unsigned rw = w * 32u;                 // wave's 32-row slice (M-split, full K)
  f32x4 z4 = {0.f, 0.f, 0.f, 0.f};
  // layer1 pack-phase bias: cq = tid&3 is constant per thread -> hoist
  float bias1[4];
  if (!is0) {
#pragma unroll
    for (int j = 0; j < 4; ++j) bias1[j] = g_b1[cbase + (tid & 3u) * 4u + j];
  }

  for (unsigned i = 0;; ++i) {
    if (is0) {
      if (i < 1024u) {                          // ---- layer0, step t = i
        const unsigned t = i;
        const unsigned long long* Ap = g_h0u[(t + 1u) & 1u];   // h0[t-1]
        f32x4 acc[2][2];
        acc[0][0] = z4; acc[0][1] = z4; acc[1][0] = z4; acc[1][1] = z4;
        for (unsigned kk = 0; kk < 16u; ++kk) { // K = 512
          unsigned k0 = kk * 32u + lko;
          bf16x8_t bfr[2];
#pragma unroll
          for (unsigned nj = 0; nj < 2u; ++nj) {
            unsigned nl = nj * 16u + lrow;
            bfr[nj] = *(const bf16x8_t*)(smem + nl * 1024u + ((2u * k0) ^ ((nl & 7u) << 4)));
          }
#pragma unroll
          for (unsigned mi = 0; mi < 2u; ++mi) {
            unsigned m = rw + mi * 16u + lrow;
            bf16x8_t afr = ld_a16(Ap + ((m * 512u + k0) >> 2));
#pragma unroll
            for (unsigned nj = 0; nj < 2u; ++nj)
              acc[mi][nj] = __builtin_amdgcn_mfma_f32_16x16x32_bf16(afr, bfr[nj], acc[mi][nj], 0, 0, 0);
          }
        }
        // stage f32 tile [4 waves][32r][32c]
#pragma unroll
        for (unsigned mi = 0; mi < 2u; ++mi)
#pragma unroll
          for (unsigned nj = 0; nj < 2u; ++nj)
#pragma unroll
            for (unsigned r = 0; r < 4u; ++r)
              stage[w * 1024u + (mi * 16u + crow + r) * 32u + nj * 16u + lrow] = acc[mi][nj][r];
        __syncthreads();
        // pack: + pre0, tanh, 4x bf16 -> one 8B IC store
        for (unsigned idx = tid; idx < 1024u; idx += 256u) {
          unsigned row = idx >> 3, cq = idx & 7u;
          unsigned wv = row >> 5, lr = row & 31u;
          const float* sp = stage + wv * 1024u + lr * 32u + cq * 4u;
          unsigned long long p0 = *(const unsigned long long*)(g_pre0 + ((size_t)t * 128u + row) * 512u + cbase + cq * 4u);
          unsigned long long outv = 0ull;
#pragma unroll
          for (int j = 0; j < 4; ++j) {
            float f = sp[j] + bf2f((unsigned short)(p0 >> (16 * j)));
            outv |= ((unsigned long long)f2bf(tanh_fast(f))) << (16 * j);
          }
          st_a8(&g_h0u[t & 1u][(row * 512u + cbase + cq * 4u) >> 2], outv);
        }
      }
    } else {
      if (i >= 1u) {                            // ---- layer1, step t1 = i-1 (pipelined)
        const unsigned t1 = i - 1u;
        const unsigned long long* A0 = g_h0u[t1 & 1u];         // h0[t1]
        const unsigned long long* A1 = g_h1u[(t1 + 1u) & 1u];  // h1[t1-1]
        f32x4 acc[2];
        acc[0] = z4; acc[1] = z4;
        for (unsigned kk = 0; kk < 32u; ++kk) { // K = 1024
          unsigned kg = kk * 32u + lko;
          bf16x8_t bfr = *(const bf16x8_t*)(smem + lrow * 2048u + ((2u * kg) ^ ((lrow & 7u) << 4)));
          const unsigned long long* Ap = (kg < 512u) ? A0 : A1;
          unsigned kl = kg & 511u;
#pragma unroll
          for (unsigned mi = 0; mi < 2u; ++mi) {
            unsigned m = rw + mi * 16u + lrow;
            bf16x8_t afr = ld_a16(Ap + ((m * 512u + kl) >> 2));
            acc[mi] = __builtin_amdgcn_mfma_f32_16x16x32_bf16(afr, bfr, acc[mi], 0, 0, 0);
          }
        }
        // stage f32 tile [4 waves][32r][16c]
#pragma unroll
        for (unsigned mi = 0; mi < 2u; ++mi)
#pragma unroll
          for (unsigned r = 0; r < 4u; ++r)
            stage[w * 512u + (mi * 16u + crow + r) * 16u + lrow] = acc[mi][r];
        __syncthreads();
        for (unsigned idx = tid; idx < 512u; idx += 256u) {
          unsigned row = idx >> 2, cq = idx & 3u;
          unsigned wv = row >> 5, lr = row & 31u;
          const float* sp = stage + wv * 512u + lr * 16u + cq * 4u;
          unsigned long long outv = 0ull;
#pragma unroll
          for (int j = 0; j < 4; ++j) {
            float f = sp[j] + bias1[j];
            outv |= ((unsigned long long)f2bf(tanh_fast(f))) << (16 * j);
          }
          st_a8(&g_h1u[t1 & 1u][(row * 512u + cbase + cq * 4u) >> 2], outv);
        }
      }
    }
    if (i == 1024u) break;                      // last data visible to fc via kernel boundary

    // ---- all-to-all flag barrier (relaxed stores + relaxed polls; no cache ops) ----
    __syncthreads();                            // drains vmcnt(0): IC stores complete
    if (tid == 0u)
      __hip_atomic_store(&g_flag[wg], i + 1u, __ATOMIC_RELAXED, __HIP_MEMORY_SCOPE_AGENT);
    if (w == 0u && lane < NWG) {
      unsigned spins = 0u;
      while (__hip_atomic_load(&g_flag[lane], __ATOMIC_RELAXED, __HIP_MEMORY_SCOPE_AGENT) < i + 1u) {
        if (((++spins) & 255u) == 0u)           // staleness safety valve (should never fire)
          (void)__hip_atomic_load(&g_flag[lane], __ATOMIC_ACQUIRE, __HIP_MEMORY_SCOPE_AGENT);
      }
    }
    __builtin_amdgcn_fence(__ATOMIC_ACQUIRE, "workgroup");  // compiler/wait ordering only
    __syncthreads();
  }
}

// ---------------------------------------------------------------- fc: h1_final @ fc_w^T + fc_b
__global__ __launch_bounds__(256) void fc_kernel(const float* __restrict__ fc_w,
                                                 const float* __restrict__ fc_b,
                                                 float* __restrict__ out) {
  const unsigned wg = blockIdx.x;
  const unsigned lane = threadIdx.x & 63u, w = threadIdx.x >> 6;
  const unsigned lrow = lane & 15u, lko = (lane >> 4) * 8u, crow = (lane >> 4) * 4u;
  const unsigned n0 = wg * 64u + w * 16u;
  const unsigned short* __restrict__ h1 = (const unsigned short*)&g_h1u[1][0];  // slot(1023)
  f32x4 z4 = {0.f, 0.f, 0.f, 0.f};
  f32x4 acc[8];
#pragma unroll
  for (int a = 0; a < 8; ++a) acc[a] = z4;
  const unsigned n = n0 + lrow;
  for (unsigned kk = 0; kk < 16u; ++kk) {
    unsigned k0 = kk * 32u + lko;
    bf16x8_t bfr = {0, 0, 0, 0, 0, 0, 0, 0};
    if (n < 1000u) bfr = cvt8f(fc_w + n * 512u + k0);
#pragma unroll
    for (unsigned mi = 0; mi < 8u; ++mi) {
      bf16x8_t afr = *(const bf16x8_t*)(h1 + (mi * 16u + lrow) * 512u + k0);
      acc[mi] = __builtin_amdgcn_mfma_f32_16x16x32_bf16(afr, bfr, acc[mi], 0, 0, 0);
    }
  }
#pragma unroll
  for (unsigned mi = 0; mi < 8u; ++mi)
#pragma unroll
    for (unsigned r = 0; r < 4u; ++r) {
      unsigned row = mi * 16u + crow + r;
      unsigned col = n0 + lrow;
      if (col < 1000u) out[row * 1000u + col] = acc[mi][r] + fc_b[col];
    }
}

// ---------------------------------------------------------------- launch
extern "C" void kernel_launch(void* const* d_in, const int* in_sizes, int n_in,
                              void* d_out, int out_size, void* d_ws, size_t ws_size,
                              hipStream_t stream) {
  (void)in_sizes; (void)n_in; (void)out_size; (void)d_ws; (void)ws_size;
  const float* x     = (const float*)d_in[0];
  const float* Wx0_w = (const float*)d_in[1];
  const float* Wx0_b = (const float*)d_in[2];
  const float* Wh0_w = (const float*)d_in[3];
  const float* Wh0_b = (const float*)d_in[4];
  const float* Wx1_w = (const float*)d_in[5];
  const float* Wx1_b = (const float*)d_in[6];
  const float* Wh1_w = (const float*)d_in[7];
  const float* Wh1_b = (const float*)d_in[8];
  const float* fc_w  = (const float*)d_in[9];
  const float* fc_b  = (const float*)d_in[10];

  prep_kernel<<<1024, 256, 0, stream>>>(Wh0_w, Wx1_w, Wh1_w, Wx1_b, Wh1_b);
  pre0_kernel<<<1024, 512, 0, stream>>>(x, Wx0_w, Wx0_b, Wh0_b);
  rnn_kernel<<<NWG, 256, 0, stream>>>();
  fc_kernel<<<16, 256, 0, stream>>>(fc_w, fc_b, (float*)d_out);
}

// Round 3
// 12832.440 us; speedup vs baseline: 2.8237x; 1.5039x over previous
//
#include <hip/hip_runtime.h>

// MultiLayerRNN: B=128, T=1024, D_IN=256, H=512, C=1000
// Round 3: plain cached loads for h (+1 acquire-agent fence per step = one
// buffer_inv), relaxed sc1 atomic stores for h, register prefetch of pre0.
//   - 48 WGs: 16 layer0 (128r x 32c) + 32 layer1 (128r x 16c), waves M-split
//   - all-to-all flag barrier (relaxed store + relaxed polls)

#define NWG 48u
#define NWG0 16u

typedef __attribute__((ext_vector_type(8))) short bf16x8_t;
typedef __attribute__((ext_vector_type(4))) float f32x4;

__device__ __align__(16) unsigned short g_Wh0[512 * 512];        // bf16 [n][k]
__device__ __align__(16) unsigned short g_W1[512 * 1024];        // bf16 [n][1024] = [Wx1 | Wh1]
__device__ float g_b1[512];
__device__ __align__(16) unsigned short g_pre0[1024 * 128 * 512]; // bf16 [t][b][n]
__device__ __align__(16) unsigned long long g_h0u[2][16384];      // bf16x4 ring
__device__ __align__(16) unsigned long long g_h1u[2][16384];
__device__ unsigned g_flag[64];

__device__ __forceinline__ unsigned short f2bf(float f) {
  unsigned u = __float_as_uint(f);
  u += 0x7fffu + ((u >> 16) & 1u);   // RNE
  return (unsigned short)(u >> 16);
}
__device__ __forceinline__ float bf2f(unsigned short h) {
  return __uint_as_float(((unsigned)h) << 16);
}
__device__ __forceinline__ bf16x8_t cvt8f(const float* p) {
  bf16x8_t r;
#pragma unroll
  for (int i = 0; i < 8; ++i) r[i] = (short)f2bf(p[i]);
  return r;
}
__device__ __forceinline__ float tanh_fast(float x) {
  float e = __expf(2.f * x);
  return 1.f - 2.f / (e + 1.f);
}
__device__ __forceinline__ void st_a8(unsigned long long* p, unsigned long long v) {
  __hip_atomic_store(p, v, __ATOMIC_RELAXED, __HIP_MEMORY_SCOPE_AGENT);
}

// ---------------------------------------------------------------- prep
__global__ void prep_kernel(const float* __restrict__ Wh0_w, const float* __restrict__ Wx1_w,
                            const float* __restrict__ Wh1_w, const float* __restrict__ Wx1_b,
                            const float* __restrict__ Wh1_b) {
  unsigned tid = blockIdx.x * blockDim.x + threadIdx.x;
  unsigned stride = gridDim.x * blockDim.x;
  for (unsigned i = tid; i < 512u * 512u; i += stride) g_Wh0[i] = f2bf(Wh0_w[i]);
  for (unsigned i = tid; i < 512u * 1024u; i += stride) {
    unsigned n = i >> 10, k = i & 1023u;
    float v = (k < 512u) ? Wx1_w[n * 512u + k] : Wh1_w[n * 512u + k - 512u];
    g_W1[i] = f2bf(v);
  }
  for (unsigned i = tid; i < 512u; i += stride) g_b1[i] = Wx1_b[i] + Wh1_b[i];
  unsigned long long* h0p = &g_h0u[0][0];
  unsigned long long* h1p = &g_h1u[0][0];
  for (unsigned i = tid; i < 2u * 16384u; i += stride) { h0p[i] = 0ull; h1p[i] = 0ull; }
  for (unsigned i = tid; i < 64u; i += stride) g_flag[i] = 0u;
}

// ---------------------------------------------------------------- pre0: x @ Wx0^T + biases
__global__ __launch_bounds__(512) void pre0_kernel(const float* __restrict__ x,
                                                   const float* __restrict__ Wx0_w,
                                                   const float* __restrict__ Wx0_b,
                                                   const float* __restrict__ Wh0_b) {
  const unsigned t = blockIdx.x;
  const unsigned lane = threadIdx.x & 63u, w = threadIdx.x >> 6;
  const unsigned lrow = lane & 15u, lko = (lane >> 4) * 8u, crow = (lane >> 4) * 4u;
  const unsigned ncol0 = w * 64u;
  f32x4 z4 = {0.f, 0.f, 0.f, 0.f};
  f32x4 acc[8][4];
#pragma unroll
  for (int a = 0; a < 8; ++a)
#pragma unroll
    for (int b = 0; b < 4; ++b) acc[a][b] = z4;

  for (unsigned kk = 0; kk < 8u; ++kk) {
    unsigned k0 = kk * 32u + lko;
    bf16x8_t bfr[4];
#pragma unroll
    for (unsigned nj = 0; nj < 4u; ++nj) {
      unsigned n = ncol0 + nj * 16u + lrow;
      bfr[nj] = cvt8f(Wx0_w + n * 256u + k0);
    }
#pragma unroll
    for (unsigned mi = 0; mi < 8u; ++mi) {
      unsigned m = mi * 16u + lrow;
      bf16x8_t afr = cvt8f(x + ((size_t)m * 1024u + t) * 256u + k0);
#pragma unroll
      for (unsigned nj = 0; nj < 4u; ++nj)
        acc[mi][nj] = __builtin_amdgcn_mfma_f32_16x16x32_bf16(afr, bfr[nj], acc[mi][nj], 0, 0, 0);
    }
  }
#pragma unroll
  for (unsigned mi = 0; mi < 8u; ++mi)
#pragma unroll
    for (unsigned nj = 0; nj < 4u; ++nj)
#pragma unroll
      for (unsigned r = 0; r < 4u; ++r) {
        unsigned row = mi * 16u + crow + r;
        unsigned col = ncol0 + nj * 16u + lrow;
        float v = acc[mi][nj][r] + Wx0_b[col] + Wh0_b[col];
        g_pre0[((size_t)t * 128u + row) * 512u + col] = f2bf(v);
      }
}

// ---------------------------------------------------------------- persistent recurrence
__global__ __launch_bounds__(256) void rnn_kernel() {
  const unsigned wg = blockIdx.x;
  const unsigned tid = threadIdx.x;
  const unsigned lane = tid & 63u, w = tid >> 6;
  const unsigned lrow = lane & 15u, lko = (lane >> 4) * 8u, crow = (lane >> 4) * 4u;
  __shared__ __align__(16) unsigned char smem[49152];     // 32KB weights + 16KB f32 stage
  float* stage = (float*)(smem + 32768);
  const bool is0 = (wg < NWG0);
  const unsigned cbase = is0 ? (wg * 32u) : ((wg - NWG0) * 16u);

  // stage weight slice into LDS once, XOR-swizzled
  if (is0) {
    for (unsigned idx = tid; idx < 32u * 64u; idx += 256u) {
      unsigned row = idx >> 6, ko = idx & 63u;
      uint4 v = *(const uint4*)(g_Wh0 + (cbase + row) * 512u + ko * 8u);
      *(uint4*)(smem + row * 1024u + ((ko * 16u) ^ ((row & 7u) << 4))) = v;
    }
  } else {
    for (unsigned idx = tid; idx < 16u * 128u; idx += 256u) {
      unsigned row = idx >> 7, ko = idx & 127u;
      uint4 v = *(const uint4*)(g_W1 + (cbase + row) * 1024u + ko * 8u);
      *(uint4*)(smem + row * 2048u + ((ko * 16u) ^ ((row & 7u) << 4))) = v;
    }
  }
  __syncthreads();

  const unsigned rw = w * 32u;                 // wave's 32-row slice (M-split, full K)
  f32x4 z4 = {0.f, 0.f, 0.f, 0.f};
  float bias1[4];
  if (!is0) {
#pragma unroll
    for (int j = 0; j < 4; ++j) bias1[j] = g_b1[cbase + (tid & 3u) * 4u + j];
  }

  for (unsigned i = 0;; ++i) {
    // one cache-invalidate per step: everything after this sees the IC-fresh h
    if (i) __builtin_amdgcn_fence(__ATOMIC_ACQUIRE, "agent");

    if (is0) {
      if (i < 1024u) {                          // ---- layer0, step t = i
        const unsigned t = i;
        // prefetch pre0 for the pack phase (HBM latency hides under K-loop)
        unsigned long long p0v[4];
#pragma unroll
        for (unsigned q = 0; q < 4u; ++q) {
          unsigned idx2 = tid + q * 256u;
          unsigned row = idx2 >> 3, cq = idx2 & 7u;
          p0v[q] = *(const unsigned long long*)(g_pre0 + ((size_t)t * 128u + row) * 512u + cbase + cq * 4u);
        }
        const unsigned short* __restrict__ Ap = (const unsigned short*)&g_h0u[(t + 1u) & 1u][0];
        f32x4 acc[2][2];
        acc[0][0] = z4; acc[0][1] = z4; acc[1][0] = z4; acc[1][1] = z4;
#pragma unroll 4
        for (unsigned kk = 0; kk < 16u; ++kk) { // K = 512
          unsigned k0 = kk * 32u + lko;
          bf16x8_t afr0 = *(const bf16x8_t*)(Ap + (rw + lrow) * 512u + k0);
          bf16x8_t afr1 = *(const bf16x8_t*)(Ap + (rw + 16u + lrow) * 512u + k0);
          bf16x8_t bfr[2];
#pragma unroll
          for (unsigned nj = 0; nj < 2u; ++nj) {
            unsigned nl = nj * 16u + lrow;
            bfr[nj] = *(const bf16x8_t*)(smem + nl * 1024u + ((2u * k0) ^ ((nl & 7u) << 4)));
          }
          acc[0][0] = __builtin_amdgcn_mfma_f32_16x16x32_bf16(afr0, bfr[0], acc[0][0], 0, 0, 0);
          acc[0][1] = __builtin_amdgcn_mfma_f32_16x16x32_bf16(afr0, bfr[1], acc[0][1], 0, 0, 0);
          acc[1][0] = __builtin_amdgcn_mfma_f32_16x16x32_bf16(afr1, bfr[0], acc[1][0], 0, 0, 0);
          acc[1][1] = __builtin_amdgcn_mfma_f32_16x16x32_bf16(afr1, bfr[1], acc[1][1], 0, 0, 0);
        }
        // stage f32 tile [4 waves][32r][32c]
#pragma unroll
        for (unsigned mi = 0; mi < 2u; ++mi)
#pragma unroll
          for (unsigned nj = 0; nj < 2u; ++nj)
#pragma unroll
            for (unsigned r = 0; r < 4u; ++r)
              stage[w * 1024u + (mi * 16u + crow + r) * 32u + nj * 16u + lrow] = acc[mi][nj][r];
        __syncthreads();
        // pack: + pre0, tanh, 4x bf16 -> one 8B IC store
#pragma unroll
        for (unsigned q = 0; q < 4u; ++q) {
          unsigned idx2 = tid + q * 256u;
          unsigned row = idx2 >> 3, cq = idx2 & 7u;
          unsigned wv = row >> 5, lr = row & 31u;
          const float* sp = stage + wv * 1024u + lr * 32u + cq * 4u;
          unsigned long long p0 = p0v[q];
          unsigned long long outv = 0ull;
#pragma unroll
          for (int j = 0; j < 4; ++j) {
            float f = sp[j] + bf2f((unsigned short)(p0 >> (16 * j)));
            outv |= ((unsigned long long)f2bf(tanh_fast(f))) << (16 * j);
          }
          st_a8(&g_h0u[t & 1u][(row * 512u + cbase + cq * 4u) >> 2], outv);
        }
      }
    } else {
      if (i >= 1u) {                            // ---- layer1, step t1 = i-1 (pipelined)
        const unsigned t1 = i - 1u;
        const unsigned short* __restrict__ A0 = (const unsigned short*)&g_h0u[t1 & 1u][0];
        const unsigned short* __restrict__ A1 = (const unsigned short*)&g_h1u[(t1 + 1u) & 1u][0];
        f32x4 acc[2];
        acc[0] = z4; acc[1] = z4;
#pragma unroll 4
        for (unsigned kk = 0; kk < 32u; ++kk) { // K = 1024 ([h0 | h1])
          unsigned kg = kk * 32u + lko;
          const unsigned short* Ap = (kg < 512u) ? A0 : A1;
          unsigned kl = kg & 511u;
          bf16x8_t afr0 = *(const bf16x8_t*)(Ap + (rw + lrow) * 512u + kl);
          bf16x8_t afr1 = *(const bf16x8_t*)(Ap + (rw + 16u + lrow) * 512u + kl);
          bf16x8_t bfr = *(const bf16x8_t*)(smem + lrow * 2048u + ((2u * kg) ^ ((lrow & 7u) << 4)));
          acc[0] = __builtin_amdgcn_mfma_f32_16x16x32_bf16(afr0, bfr, acc[0], 0, 0, 0);
          acc[1] = __builtin_amdgcn_mfma_f32_16x16x32_bf16(afr1, bfr, acc[1], 0, 0, 0);
        }
        // stage f32 tile [4 waves][32r][16c]
#pragma unroll
        for (unsigned mi = 0; mi < 2u; ++mi)
#pragma unroll
          for (unsigned r = 0; r < 4u; ++r)
            stage[w * 512u + (mi * 16u + crow + r) * 16u + lrow] = acc[mi][r];
        __syncthreads();
#pragma unroll
        for (unsigned q = 0; q < 2u; ++q) {
          unsigned idx2 = tid + q * 256u;
          unsigned row = idx2 >> 2, cq = idx2 & 3u;
          unsigned wv = row >> 5, lr = row & 31u;
          const float* sp = stage + wv * 512u + lr * 16u + cq * 4u;
          unsigned long long outv = 0ull;
#pragma unroll
          for (int j = 0; j < 4; ++j) {
            float f = sp[j] + bias1[j];
            outv |= ((unsigned long long)f2bf(tanh_fast(f))) << (16 * j);
          }
          st_a8(&g_h1u[t1 & 1u][(row * 512u + cbase + cq * 4u) >> 2], outv);
        }
      }
    }
    if (i == 1024u) break;                      // fc sees final h1 via kernel boundary

    // ---- all-to-all flag barrier (relaxed stores + relaxed polls) ----
    __syncthreads();                            // waitcnt vmcnt(0) before s_barrier: stores done
    if (tid == 0u)
      __hip_atomic_store(&g_flag[wg], i + 1u, __ATOMIC_RELAXED, __HIP_MEMORY_SCOPE_AGENT);
    if (w == 0u && lane < NWG) {
      while (__hip_atomic_load(&g_flag[lane], __ATOMIC_RELAXED, __HIP_MEMORY_SCOPE_AGENT) < i + 1u) {}
    }
    __syncthreads();
  }
}

// ---------------------------------------------------------------- fc: h1_final @ fc_w^T + fc_b
__global__ __launch_bounds__(256) void fc_kernel(const float* __restrict__ fc_w,
                                                 const float* __restrict__ fc_b,
                                                 float* __restrict__ out) {
  const unsigned wg = blockIdx.x;
  const unsigned lane = threadIdx.x & 63u, w = threadIdx.x >> 6;
  const unsigned lrow = lane & 15u, lko = (lane >> 4) * 8u, crow = (lane >> 4) * 4u;
  const unsigned n0 = wg * 64u + w * 16u;
  const unsigned short* __restrict__ h1 = (const unsigned short*)&g_h1u[1][0];  // slot(1023)
  f32x4 z4 = {0.f, 0.f, 0.f, 0.f};
  f32x4 acc[8];
#pragma unroll
  for (int a = 0; a < 8; ++a) acc[a] = z4;
  const unsigned n = n0 + lrow;
  for (unsigned kk = 0; kk < 16u; ++kk) {
    unsigned k0 = kk * 32u + lko;
    bf16x8_t bfr = {0, 0, 0, 0, 0, 0, 0, 0};
    if (n < 1000u) bfr = cvt8f(fc_w + n * 512u + k0);
#pragma unroll
    for (unsigned mi = 0; mi < 8u; ++mi) {
      bf16x8_t afr = *(const bf16x8_t*)(h1 + (mi * 16u + lrow) * 512u + k0);
      acc[mi] = __builtin_amdgcn_mfma_f32_16x16x32_bf16(afr, bfr, acc[mi], 0, 0, 0);
    }
  }
#pragma unroll
  for (unsigned mi = 0; mi < 8u; ++mi)
#pragma unroll
    for (unsigned r = 0; r < 4u; ++r) {
      unsigned row = mi * 16u + crow + r;
      unsigned col = n0 + lrow;
      if (col < 1000u) out[row * 1000u + col] = acc[mi][r] + fc_b[col];
    }
}

// ---------------------------------------------------------------- launch
extern "C" void kernel_launch(void* const* d_in, const int* in_sizes, int n_in,
                              void* d_out, int out_size, void* d_ws, size_t ws_size,
                              hipStream_t stream) {
  (void)in_sizes; (void)n_in; (void)out_size; (void)d_ws; (void)ws_size;
  const float* x     = (const float*)d_in[0];
  const float* Wx0_w = (const float*)d_in[1];
  const float* Wx0_b = (const float*)d_in[2];
  const float* Wh0_w = (const float*)d_in[3];
  const float* Wh0_b = (const float*)d_in[4];
  const float* Wx1_w = (const float*)d_in[5];
  const float* Wx1_b = (const float*)d_in[6];
  const float* Wh1_w = (const float*)d_in[7];
  const float* Wh1_b = (const float*)d_in[8];
  const float* fc_w  = (const float*)d_in[9];
  const float* fc_b  = (const float*)d_in[10];

  prep_kernel<<<1024, 256, 0, stream>>>(Wh0_w, Wx1_w, Wh1_w, Wx1_b, Wh1_b);
  pre0_kernel<<<1024, 512, 0, stream>>>(x, Wx0_w, Wx0_b, Wh0_b);
  rnn_kernel<<<NWG, 256, 0, stream>>>();
  fc_kernel<<<16, 256, 0, stream>>>(fc_w, fc_b, (float*)d_out);
}

// Round 4
// 10570.801 us; speedup vs baseline: 3.4279x; 1.2140x over previous
//
#include <hip/hip_runtime.h>

// MultiLayerRNN: B=128, T=1024, D_IN=256, H=512, C=1000
// Round 4: NO cache-invalidating fence anywhere in the hot loop.
//   - pre0/weights: plain cached loads (L2 stays warm)
//   - h loads: inline-asm global_load_dwordx4 sc1 (coherent IC reads),
//     hand-pipelined 2-deep with counted s_waitcnt vmcnt(8)
//   - h stores: relaxed agent atomics (sc1, write-through to IC)
//   - all-to-all flag barrier (relaxed store + relaxed polls)
//   - 48 WGs: 16 layer0 (128r x 32c) + 32 layer1 (128r x 16c), waves M-split

#define NWG 48u
#define NWG0 16u

typedef __attribute__((ext_vector_type(8))) short bf16x8_t;
typedef __attribute__((ext_vector_type(4))) float f32x4;

__device__ __align__(16) unsigned short g_Wh0[512 * 512];        // bf16 [n][k]
__device__ __align__(16) unsigned short g_W1[512 * 1024];        // bf16 [n][1024] = [Wx1 | Wh1]
__device__ float g_b1[512];
__device__ __align__(16) unsigned short g_pre0[1024 * 128 * 512]; // bf16 [t][b][n]
__device__ __align__(16) unsigned long long g_h0u[2][16384];      // bf16x4 ring
__device__ __align__(16) unsigned long long g_h1u[2][16384];
__device__ unsigned g_flag[64];

__device__ __forceinline__ unsigned short f2bf(float f) {
  unsigned u = __float_as_uint(f);
  u += 0x7fffu + ((u >> 16) & 1u);   // RNE
  return (unsigned short)(u >> 16);
}
__device__ __forceinline__ float bf2f(unsigned short h) {
  return __uint_as_float(((unsigned)h) << 16);
}
__device__ __forceinline__ bf16x8_t cvt8f(const float* p) {
  bf16x8_t r;
#pragma unroll
  for (int i = 0; i < 8; ++i) r[i] = (short)f2bf(p[i]);
  return r;
}
__device__ __forceinline__ float tanh_fast(float x) {
  float e = __expf(2.f * x);
  return 1.f - 2.f / (e + 1.f);
}
__device__ __forceinline__ void st_a8(unsigned long long* p, unsigned long long v) {
  __hip_atomic_store(p, v, __ATOMIC_RELAXED, __HIP_MEMORY_SCOPE_AGENT);
}

#define MF(a, b, c) __builtin_amdgcn_mfma_f32_16x16x32_bf16(a, b, c, 0, 0, 0)
// coherent 16B load from IC (same sc1 semantics the compiler emits for
// agent-scope relaxed atomic loads; proven correct in round 2)
#define LDG16(dst, base, OFF) \
  asm volatile("global_load_dwordx4 %0, %1, off offset:" #OFF " sc1" : "=v"(dst) : "v"(base))
#define ISSUE8(p, B0, B1, O0, O1, O2, O3) \
  LDG16(p##0, B0, O0); LDG16(p##1, B1, O0); \
  LDG16(p##2, B0, O1); LDG16(p##3, B1, O1); \
  LDG16(p##4, B0, O2); LDG16(p##5, B1, O2); \
  LDG16(p##6, B0, O3); LDG16(p##7, B1, O3)
#define WAITV(N) do { \
    asm volatile("s_waitcnt vmcnt(" #N ")" ::: "memory"); \
    __builtin_amdgcn_sched_barrier(0); \
  } while (0)
// layer0 consume: 4 kk, A-frags p##0..p##7 (row0/row1 pairs), B from LDS rows lrow and 16+lrow
#define CONS_L0(p, KB2) { \
    unsigned o_; bf16x8_t bf0_, bf1_; \
    o_ = ((KB2) + 0u + koByte) ^ swzB; bf0_ = *(const bf16x8_t*)(bR0 + o_); bf1_ = *(const bf16x8_t*)(bR1 + o_); \
    a00 = MF(p##0, bf0_, a00); a01 = MF(p##0, bf1_, a01); a10 = MF(p##1, bf0_, a10); a11 = MF(p##1, bf1_, a11); \
    o_ = ((KB2) + 64u + koByte) ^ swzB; bf0_ = *(const bf16x8_t*)(bR0 + o_); bf1_ = *(const bf16x8_t*)(bR1 + o_); \
    a00 = MF(p##2, bf0_, a00); a01 = MF(p##2, bf1_, a01); a10 = MF(p##3, bf0_, a10); a11 = MF(p##3, bf1_, a11); \
    o_ = ((KB2) + 128u + koByte) ^ swzB; bf0_ = *(const bf16x8_t*)(bR0 + o_); bf1_ = *(const bf16x8_t*)(bR1 + o_); \
    a00 = MF(p##4, bf0_, a00); a01 = MF(p##4, bf1_, a01); a10 = MF(p##5, bf0_, a10); a11 = MF(p##5, bf1_, a11); \
    o_ = ((KB2) + 192u + koByte) ^ swzB; bf0_ = *(const bf16x8_t*)(bR0 + o_); bf1_ = *(const bf16x8_t*)(bR1 + o_); \
    a00 = MF(p##6, bf0_, a00); a01 = MF(p##6, bf1_, a01); a10 = MF(p##7, bf0_, a10); a11 = MF(p##7, bf1_, a11); \
  }
// layer1 consume: 4 kk, one B frag per kk
#define CONS_L1(p, KB2) { \
    unsigned o_; bf16x8_t bf_; \
    o_ = ((KB2) + 0u + koByte) ^ swzB; bf_ = *(const bf16x8_t*)(bRow + o_); \
    acc0 = MF(p##0, bf_, acc0); acc1 = MF(p##1, bf_, acc1); \
    o_ = ((KB2) + 64u + koByte) ^ swzB; bf_ = *(const bf16x8_t*)(bRow + o_); \
    acc0 = MF(p##2, bf_, acc0); acc1 = MF(p##3, bf_, acc1); \
    o_ = ((KB2) + 128u + koByte) ^ swzB; bf_ = *(const bf16x8_t*)(bRow + o_); \
    acc0 = MF(p##4, bf_, acc0); acc1 = MF(p##5, bf_, acc1); \
    o_ = ((KB2) + 192u + koByte) ^ swzB; bf_ = *(const bf16x8_t*)(bRow + o_); \
    acc0 = MF(p##6, bf_, acc0); acc1 = MF(p##7, bf_, acc1); \
  }

// ---------------------------------------------------------------- prep
__global__ void prep_kernel(const float* __restrict__ Wh0_w, const float* __restrict__ Wx1_w,
                            const float* __restrict__ Wh1_w, const float* __restrict__ Wx1_b,
                            const float* __restrict__ Wh1_b) {
  unsigned tid = blockIdx.x * blockDim.x + threadIdx.x;
  unsigned stride = gridDim.x * blockDim.x;
  for (unsigned i = tid; i < 512u * 512u; i += stride) g_Wh0[i] = f2bf(Wh0_w[i]);
  for (unsigned i = tid; i < 512u * 1024u; i += stride) {
    unsigned n = i >> 10, k = i & 1023u;
    float v = (k < 512u) ? Wx1_w[n * 512u + k] : Wh1_w[n * 512u + k - 512u];
    g_W1[i] = f2bf(v);
  }
  for (unsigned i = tid; i < 512u; i += stride) g_b1[i] = Wx1_b[i] + Wh1_b[i];
  unsigned long long* h0p = &g_h0u[0][0];
  unsigned long long* h1p = &g_h1u[0][0];
  for (unsigned i = tid; i < 2u * 16384u; i += stride) { h0p[i] = 0ull; h1p[i] = 0ull; }
  for (unsigned i = tid; i < 64u; i += stride) g_flag[i] = 0u;
}

// ---------------------------------------------------------------- pre0: x @ Wx0^T + biases
__global__ __launch_bounds__(512) void pre0_kernel(const float* __restrict__ x,
                                                   const float* __restrict__ Wx0_w,
                                                   const float* __restrict__ Wx0_b,
                                                   const float* __restrict__ Wh0_b) {
  const unsigned t = blockIdx.x;
  const unsigned lane = threadIdx.x & 63u, w = threadIdx.x >> 6;
  const unsigned lrow = lane & 15u, lko = (lane >> 4) * 8u, crow = (lane >> 4) * 4u;
  const unsigned ncol0 = w * 64u;
  f32x4 z4 = {0.f, 0.f, 0.f, 0.f};
  f32x4 acc[8][4];
#pragma unroll
  for (int a = 0; a < 8; ++a)
#pragma unroll
    for (int b = 0; b < 4; ++b) acc[a][b] = z4;

  for (unsigned kk = 0; kk < 8u; ++kk) {
    unsigned k0 = kk * 32u + lko;
    bf16x8_t bfr[4];
#pragma unroll
    for (unsigned nj = 0; nj < 4u; ++nj) {
      unsigned n = ncol0 + nj * 16u + lrow;
      bfr[nj] = cvt8f(Wx0_w + n * 256u + k0);
    }
#pragma unroll
    for (unsigned mi = 0; mi < 8u; ++mi) {
      unsigned m = mi * 16u + lrow;
      bf16x8_t afr = cvt8f(x + ((size_t)m * 1024u + t) * 256u + k0);
#pragma unroll
      for (unsigned nj = 0; nj < 4u; ++nj)
        acc[mi][nj] = MF(afr, bfr[nj], acc[mi][nj]);
    }
  }
#pragma unroll
  for (unsigned mi = 0; mi < 8u; ++mi)
#pragma unroll
    for (unsigned nj = 0; nj < 4u; ++nj)
#pragma unroll
      for (unsigned r = 0; r < 4u; ++r) {
        unsigned row = mi * 16u + crow + r;
        unsigned col = ncol0 + nj * 16u + lrow;
        float v = acc[mi][nj][r] + Wx0_b[col] + Wh0_b[col];
        g_pre0[((size_t)t * 128u + row) * 512u + col] = f2bf(v);
      }
}

// ---------------------------------------------------------------- persistent recurrence
__global__ __launch_bounds__(256) void rnn_kernel() {
  const unsigned wg = blockIdx.x;
  const unsigned tid = threadIdx.x;
  const unsigned lane = tid & 63u, w = tid >> 6;
  const unsigned lrow = lane & 15u, lko = (lane >> 4) * 8u, crow = (lane >> 4) * 4u;
  __shared__ __align__(16) unsigned char smem[49152];     // 32KB weights + 16KB f32 stage
  float* stage = (float*)(smem + 32768);
  const bool is0 = (wg < NWG0);
  const unsigned cbase = is0 ? (wg * 32u) : ((wg - NWG0) * 16u);

  // stage weight slice into LDS once, XOR-swizzled
  if (is0) {
    for (unsigned idx = tid; idx < 32u * 64u; idx += 256u) {
      unsigned row = idx >> 6, ko = idx & 63u;
      uint4 v = *(const uint4*)(g_Wh0 + (cbase + row) * 512u + ko * 8u);
      *(uint4*)(smem + row * 1024u + ((ko * 16u) ^ ((row & 7u) << 4))) = v;
    }
  } else {
    for (unsigned idx = tid; idx < 16u * 128u; idx += 256u) {
      unsigned row = idx >> 7, ko = idx & 127u;
      uint4 v = *(const uint4*)(g_W1 + (cbase + row) * 1024u + ko * 8u);
      *(uint4*)(smem + row * 2048u + ((ko * 16u) ^ ((row & 7u) << 4))) = v;
    }
  }
  __syncthreads();

  const unsigned rw = w * 32u;                 // wave's 32-row slice (M-split, full K)
  const unsigned koByte = lko * 2u;
  const unsigned swzB = (lrow & 7u) << 4;
  const unsigned char* bR0  = smem + lrow * 1024u;          // layer0 B rows
  const unsigned char* bR1  = smem + (16u + lrow) * 1024u;
  const unsigned char* bRow = smem + lrow * 2048u;          // layer1 B row
  f32x4 z4 = {0.f, 0.f, 0.f, 0.f};
  float bias1[4];
  if (!is0) {
#pragma unroll
    for (int j = 0; j < 4; ++j) bias1[j] = g_b1[cbase + (tid & 3u) * 4u + j];
  }

  // pre0 prefetch registers (layer0): loaded one step ahead, consumed in pack
  unsigned long long p0v0 = 0, p0v1 = 0, p0v2 = 0, p0v3 = 0;
  if (is0) {
#define PRE0_FETCH(T) { \
      unsigned i0_ = tid, i1_ = tid + 256u, i2_ = tid + 512u, i3_ = tid + 768u; \
      p0v0 = *(const unsigned long long*)(g_pre0 + ((size_t)(T) * 128u + (i0_ >> 3)) * 512u + cbase + (i0_ & 7u) * 4u); \
      p0v1 = *(const unsigned long long*)(g_pre0 + ((size_t)(T) * 128u + (i1_ >> 3)) * 512u + cbase + (i1_ & 7u) * 4u); \
      p0v2 = *(const unsigned long long*)(g_pre0 + ((size_t)(T) * 128u + (i2_ >> 3)) * 512u + cbase + (i2_ & 7u) * 4u); \
      p0v3 = *(const unsigned long long*)(g_pre0 + ((size_t)(T) * 128u + (i3_ >> 3)) * 512u + cbase + (i3_ & 7u) * 4u); \
    }
    PRE0_FETCH(0u);
  }

  for (unsigned i = 0;; ++i) {
    if (is0) {
      if (i < 1024u) {                          // ---- layer0, step t = i
        const unsigned t = i;
        const unsigned short* Ap = (const unsigned short*)&g_h0u[(t + 1u) & 1u][0];
        const unsigned short* b0 = Ap + (rw + lrow) * 512u + lko;
        const unsigned short* b1 = b0 + 16u * 512u;
        bf16x8_t xA0, xA1, xA2, xA3, xA4, xA5, xA6, xA7;
        bf16x8_t xB0, xB1, xB2, xB3, xB4, xB5, xB6, xB7;
        f32x4 a00 = z4, a01 = z4, a10 = z4, a11 = z4;
        ISSUE8(xA, b0, b1, 0, 64, 128, 192);
        ISSUE8(xB, b0, b1, 256, 320, 384, 448);
        WAITV(8); CONS_L0(xA, 0u);
        ISSUE8(xA, b0, b1, 512, 576, 640, 704);
        WAITV(8); CONS_L0(xB, 256u);
        ISSUE8(xB, b0, b1, 768, 832, 896, 960);
        WAITV(8); CONS_L0(xA, 512u);
        WAITV(0); CONS_L0(xB, 768u);
        // stage f32 tile [4 waves][32r][32c]
#pragma unroll
        for (unsigned r = 0; r < 4u; ++r) {
          stage[w * 1024u + (crow + r) * 32u + lrow]              = a00[r];
          stage[w * 1024u + (crow + r) * 32u + 16u + lrow]        = a01[r];
          stage[w * 1024u + (16u + crow + r) * 32u + lrow]        = a10[r];
          stage[w * 1024u + (16u + crow + r) * 32u + 16u + lrow]  = a11[r];
        }
        __syncthreads();
        // pack: + pre0 (prefetched), tanh, 4x bf16 -> one 8B IC store
#define PACK0(Q, P0) { \
          unsigned idx2 = tid + (Q) * 256u; \
          unsigned row = idx2 >> 3, cq = idx2 & 7u; \
          unsigned wv = row >> 5, lr = row & 31u; \
          const float* sp = stage + wv * 1024u + lr * 32u + cq * 4u; \
          unsigned long long outv = 0ull; \
          _Pragma("unroll") \
          for (int j = 0; j < 4; ++j) { \
            float f = sp[j] + bf2f((unsigned short)((P0) >> (16 * j))); \
            outv |= ((unsigned long long)f2bf(tanh_fast(f))) << (16 * j); \
          } \
          st_a8(&g_h0u[t & 1u][(row * 512u + cbase + cq * 4u) >> 2], outv); \
        }
        PACK0(0u, p0v0); PACK0(1u, p0v1); PACK0(2u, p0v2); PACK0(3u, p0v3);
      }
    } else {
      if (i >= 1u) {                            // ---- layer1, step t1 = i-1 (pipelined)
        const unsigned t1 = i - 1u;
        const unsigned short* A0 = (const unsigned short*)&g_h0u[t1 & 1u][0];
        const unsigned short* A1 = (const unsigned short*)&g_h1u[(t1 + 1u) & 1u][0];
        const unsigned short* b0 = A0 + (rw + lrow) * 512u + lko;
        const unsigned short* b1 = b0 + 16u * 512u;
        const unsigned short* c0 = A1 + (rw + lrow) * 512u + lko;
        const unsigned short* c1 = c0 + 16u * 512u;
        bf16x8_t xA0, xA1, xA2, xA3, xA4, xA5, xA6, xA7;
        bf16x8_t xB0, xB1, xB2, xB3, xB4, xB5, xB6, xB7;
        f32x4 acc0 = z4, acc1 = z4;
        ISSUE8(xA, b0, b1, 0, 64, 128, 192);
        ISSUE8(xB, b0, b1, 256, 320, 384, 448);
        WAITV(8); CONS_L1(xA, 0u);
        ISSUE8(xA, b0, b1, 512, 576, 640, 704);
        WAITV(8); CONS_L1(xB, 256u);
        ISSUE8(xB, b0, b1, 768, 832, 896, 960);
        WAITV(8); CONS_L1(xA, 512u);
        ISSUE8(xA, c0, c1, 0, 64, 128, 192);
        WAITV(8); CONS_L1(xB, 768u);
        ISSUE8(xB, c0, c1, 256, 320, 384, 448);
        WAITV(8); CONS_L1(xA, 1024u);
        ISSUE8(xA, c0, c1, 512, 576, 640, 704);
        WAITV(8); CONS_L1(xB, 1280u);
        ISSUE8(xB, c0, c1, 768, 832, 896, 960);
        WAITV(8); CONS_L1(xA, 1536u);
        WAITV(0); CONS_L1(xB, 1792u);
        // stage f32 tile [4 waves][32r][16c]
#pragma unroll
        for (unsigned r = 0; r < 4u; ++r) {
          stage[w * 512u + (crow + r) * 16u + lrow]       = acc0[r];
          stage[w * 512u + (16u + crow + r) * 16u + lrow] = acc1[r];
        }
        __syncthreads();
#pragma unroll
        for (unsigned q = 0; q < 2u; ++q) {
          unsigned idx2 = tid + q * 256u;
          unsigned row = idx2 >> 2, cq = idx2 & 3u;
          unsigned wv = row >> 5, lr = row & 31u;
          const float* sp = stage + wv * 512u + lr * 16u + cq * 4u;
          unsigned long long outv = 0ull;
#pragma unroll
          for (int j = 0; j < 4; ++j) {
            float f = sp[j] + bias1[j];
            outv |= ((unsigned long long)f2bf(tanh_fast(f))) << (16 * j);
          }
          st_a8(&g_h1u[t1 & 1u][(row * 512u + cbase + cq * 4u) >> 2], outv);
        }
      }
    }
    if (i == 1024u) break;                      // fc sees final h1 via kernel boundary

    // prefetch next step's pre0 (hides HBM latency under the barrier)
    if (is0 && (i + 1u) < 1024u) PRE0_FETCH(i + 1u);

    // ---- all-to-all flag barrier (relaxed stores + relaxed polls) ----
    __syncthreads();                            // vmcnt(0) before s_barrier: h stores complete
    if (tid == 0u)
      __hip_atomic_store(&g_flag[wg], i + 1u, __ATOMIC_RELAXED, __HIP_MEMORY_SCOPE_AGENT);
    if (w == 0u && lane < NWG) {
      while (__hip_atomic_load(&g_flag[lane], __ATOMIC_RELAXED, __HIP_MEMORY_SCOPE_AGENT) < i + 1u) {}
    }
    __syncthreads();
  }
}

// ---------------------------------------------------------------- fc: h1_final @ fc_w^T + fc_b
__global__ __launch_bounds__(256) void fc_kernel(const float* __restrict__ fc_w,
                                                 const float* __restrict__ fc_b,
                                                 float* __restrict__ out) {
  const unsigned wg = blockIdx.x;
  const unsigned lane = threadIdx.x & 63u, w = threadIdx.x >> 6;
  const unsigned lrow = lane & 15u, lko = (lane >> 4) * 8u, crow = (lane >> 4) * 4u;
  const unsigned n0 = wg * 64u + w * 16u;
  const unsigned short* __restrict__ h1 = (const unsigned short*)&g_h1u[1][0];  // slot(1023)
  f32x4 z4 = {0.f, 0.f, 0.f, 0.f};
  f32x4 acc[8];
#pragma unroll
  for (int a = 0; a < 8; ++a) acc[a] = z4;
  const unsigned n = n0 + lrow;
  for (unsigned kk = 0; kk < 16u; ++kk) {
    unsigned k0 = kk * 32u + lko;
    bf16x8_t bfr = {0, 0, 0, 0, 0, 0, 0, 0};
    if (n < 1000u) bfr = cvt8f(fc_w + n * 512u + k0);
#pragma unroll
    for (unsigned mi = 0; mi < 8u; ++mi) {
      bf16x8_t afr = *(const bf16x8_t*)(h1 + (mi * 16u + lrow) * 512u + k0);
      acc[mi] = MF(afr, bfr, acc[mi]);
    }
  }
#pragma unroll
  for (unsigned mi = 0; mi < 8u; ++mi)
#pragma unroll
    for (unsigned r = 0; r < 4u; ++r) {
      unsigned row = mi * 16u + crow + r;
      unsigned col = n0 + lrow;
      if (col < 1000u) out[row * 1000u + col] = acc[mi][r] + fc_b[col];
    }
}

// ---------------------------------------------------------------- launch
extern "C" void kernel_launch(void* const* d_in, const int* in_sizes, int n_in,
                              void* d_out, int out_size, void* d_ws, size_t ws_size,
                              hipStream_t stream) {
  (void)in_sizes; (void)n_in; (void)out_size; (void)d_ws; (void)ws_size;
  const float* x     = (const float*)d_in[0];
  const float* Wx0_w = (const float*)d_in[1];
  const float* Wx0_b = (const float*)d_in[2];
  const float* Wh0_w = (const float*)d_in[3];
  const float* Wh0_b = (const float*)d_in[4];
  const float* Wx1_w = (const float*)d_in[5];
  const float* Wx1_b = (const float*)d_in[6];
  const float* Wh1_w = (const float*)d_in[7];
  const float* Wh1_b = (const float*)d_in[8];
  const float* fc_w  = (const float*)d_in[9];
  const float* fc_b  = (const float*)d_in[10];

  prep_kernel<<<1024, 256, 0, stream>>>(Wh0_w, Wx1_w, Wh1_w, Wx1_b, Wh1_b);
  pre0_kernel<<<1024, 512, 0, stream>>>(x, Wx0_w, Wx0_b, Wh0_b);
  rnn_kernel<<<NWG, 256, 0, stream>>>();
  fc_kernel<<<16, 256, 0, stream>>>(fc_w, fc_b, (float*)d_out);
}

// Round 5
// 8155.116 us; speedup vs baseline: 4.4433x; 1.2962x over previous
//
#include <hip/hip_runtime.h>

// MultiLayerRNN: B=128, T=1024, D_IN=256, H=512, C=1000
// Round 5: register-resident weights, zero LDS, minimal-depth load chains.
//   Per-wave job: [16 rows x 16 cols x K=512]; B = 16 MFMA frags in VGPRs
//   (loaded once); A = 16 sc1 loads issued all-at-once (chain = 1 latency).
//   Layer1 split into U = h0@Wx1^T + b1 (f32 ring) and
//   h1 = tanh(U + h1_prev@Wh1^T) -> 3-stage pipeline, 1026 intervals.
//   96 WGs x 512 thr: [0,32) layer0, [32,64) U, [64,96) combine.
//   All-to-all flag barrier (relaxed agent store + relaxed polls).

#define NWG 96u

typedef __attribute__((ext_vector_type(8))) short bf16x8_t;
typedef __attribute__((ext_vector_type(4))) float f32x4;

__device__ __align__(16) unsigned short g_Wh0[512 * 512];         // bf16 [n][k]
__device__ __align__(16) unsigned short g_Wx1[512 * 512];
__device__ __align__(16) unsigned short g_Wh1[512 * 512];
__device__ float g_b1[512];
__device__ __align__(16) unsigned short g_pre0[1024u * 128u * 512u]; // bf16 [t][b][n]
__device__ __align__(16) unsigned short g_h0[2][65536];           // bf16 ring
__device__ __align__(16) unsigned short g_h1[2][65536];
__device__ __align__(16) float g_U[2][65536];                     // f32 ring
__device__ unsigned g_flag[128];

__device__ __forceinline__ unsigned short f2bf(float f) {
  unsigned u = __float_as_uint(f);
  u += 0x7fffu + ((u >> 16) & 1u);   // RNE
  return (unsigned short)(u >> 16);
}
__device__ __forceinline__ float bf2f(unsigned short h) {
  return __uint_as_float(((unsigned)h) << 16);
}
__device__ __forceinline__ bf16x8_t cvt8f(const float* p) {
  bf16x8_t r;
#pragma unroll
  for (int i = 0; i < 8; ++i) r[i] = (short)f2bf(p[i]);
  return r;
}
__device__ __forceinline__ float tanh_fast(float x) {
  float e = __expf(2.f * x);
  return 1.f - 2.f / (e + 1.f);
}

#define MF(a, b, c) __builtin_amdgcn_mfma_f32_16x16x32_bf16(a, b, c, 0, 0, 0)
// coherent (device-scope) loads/stores via sc1 — bypasses stale per-XCD L2
#define LDG16(dst, base, OFF) \
  asm volatile("global_load_dwordx4 %0, %1, off offset:" #OFF " sc1" : "=v"(dst) : "v"(base))
#define LDG16P(dst, base, OFF) \
  asm volatile("global_load_dwordx4 %0, %1, off offset:" #OFF : "=v"(dst) : "v"(base))
#define LDU16(dst, base, OFF) \
  asm volatile("global_load_ushort %0, %1, off offset:" #OFF : "=v"(dst) : "v"(base))
#define LDF32(dst, base, OFF) \
  asm volatile("global_load_dword %0, %1, off offset:" #OFF " sc1" : "=v"(dst) : "v"(base))
#define ST2(base, OFF, val) \
  asm volatile("global_store_short %0, %1, off offset:" #OFF " sc1" :: "v"(base), "v"(val))
#define STF(base, OFF, val) \
  asm volatile("global_store_dword %0, %1, off offset:" #OFF " sc1" :: "v"(base), "v"(val))
#define WAITV(N) do { \
    asm volatile("s_waitcnt vmcnt(" #N ")" ::: "memory"); \
    __builtin_amdgcn_sched_barrier(0); \
  } while (0)
// 16 chunk loads covering [16 rows x K=512] (one lane = 16 rows x 32k per instr)
#define ISSUE_A16(LD, B) \
  LD(x0, B, 0);   LD(x1, B, 64);  LD(x2, B, 128);  LD(x3, B, 192); \
  LD(x4, B, 256); LD(x5, B, 320); LD(x6, B, 384);  LD(x7, B, 448); \
  LD(x8, B, 512); LD(x9, B, 576); LD(x10, B, 640); LD(x11, B, 704); \
  LD(x12, B, 768); LD(x13, B, 832); LD(x14, B, 896); LD(x15, B, 960)

// ---------------------------------------------------------------- prep
__global__ void prep_kernel(const float* __restrict__ Wh0_w, const float* __restrict__ Wx1_w,
                            const float* __restrict__ Wh1_w, const float* __restrict__ Wx1_b,
                            const float* __restrict__ Wh1_b) {
  unsigned tid = blockIdx.x * blockDim.x + threadIdx.x;
  unsigned stride = gridDim.x * blockDim.x;
  for (unsigned i = tid; i < 512u * 512u; i += stride) {
    g_Wh0[i] = f2bf(Wh0_w[i]);
    g_Wx1[i] = f2bf(Wx1_w[i]);
    g_Wh1[i] = f2bf(Wh1_w[i]);
  }
  for (unsigned i = tid; i < 512u; i += stride) g_b1[i] = Wx1_b[i] + Wh1_b[i];
  unsigned short* h0p = &g_h0[0][0];
  unsigned short* h1p = &g_h1[0][0];
  for (unsigned i = tid; i < 2u * 65536u; i += stride) { h0p[i] = 0; h1p[i] = 0; }
  for (unsigned i = tid; i < 128u; i += stride) g_flag[i] = 0u;
}

// ---------------------------------------------------------------- pre0: x @ Wx0^T + biases
__global__ __launch_bounds__(512) void pre0_kernel(const float* __restrict__ x,
                                                   const float* __restrict__ Wx0_w,
                                                   const float* __restrict__ Wx0_b,
                                                   const float* __restrict__ Wh0_b) {
  const unsigned t = blockIdx.x;
  const unsigned lane = threadIdx.x & 63u, w = threadIdx.x >> 6;
  const unsigned lrow = lane & 15u, lko = (lane >> 4) * 8u, crow = (lane >> 4) * 4u;
  const unsigned ncol0 = w * 64u;
  f32x4 z4 = {0.f, 0.f, 0.f, 0.f};
  f32x4 acc[8][4];
#pragma unroll
  for (int a = 0; a < 8; ++a)
#pragma unroll
    for (int b = 0; b < 4; ++b) acc[a][b] = z4;

  for (unsigned kk = 0; kk < 8u; ++kk) {
    unsigned k0 = kk * 32u + lko;
    bf16x8_t bfr[4];
#pragma unroll
    for (unsigned nj = 0; nj < 4u; ++nj) {
      unsigned n = ncol0 + nj * 16u + lrow;
      bfr[nj] = cvt8f(Wx0_w + n * 256u + k0);
    }
#pragma unroll
    for (unsigned mi = 0; mi < 8u; ++mi) {
      unsigned m = mi * 16u + lrow;
      bf16x8_t afr = cvt8f(x + ((size_t)m * 1024u + t) * 256u + k0);
#pragma unroll
      for (unsigned nj = 0; nj < 4u; ++nj)
        acc[mi][nj] = MF(afr, bfr[nj], acc[mi][nj]);
    }
  }
#pragma unroll
  for (unsigned mi = 0; mi < 8u; ++mi)
#pragma unroll
    for (unsigned nj = 0; nj < 4u; ++nj)
#pragma unroll
      for (unsigned r = 0; r < 4u; ++r) {
        unsigned row = mi * 16u + crow + r;
        unsigned col = ncol0 + nj * 16u + lrow;
        float v = acc[mi][nj][r] + Wx0_b[col] + Wh0_b[col];
        g_pre0[((size_t)t * 128u + row) * 512u + col] = f2bf(v);
      }
}

// ---------------------------------------------------------------- persistent recurrence
__global__ __launch_bounds__(512) void rnn_kernel() {
  const unsigned wg = blockIdx.x;
  const unsigned tid = threadIdx.x;
  const unsigned lane = tid & 63u, w = tid >> 6;
  const unsigned lrow = lane & 15u, lko = (lane >> 4) * 8u, crow4 = (lane >> 4) * 4u;
  const unsigned role = wg >> 5;              // 0=layer0, 1=U, 2=combine
  const unsigned cbase = (wg & 31u) * 16u;    // 16-col slice
  const unsigned rw = w * 16u;                // 16-row slice per wave

  // ---- B weights -> registers, once (16 frags = 64 VGPR) ----
  const unsigned short* wsrc = (role == 0u) ? g_Wh0 : (role == 1u) ? g_Wx1 : g_Wh1;
  const unsigned short* wbp = wsrc + (cbase + lrow) * 512u + lko;
  bf16x8_t w0, w1, w2, w3, w4, w5, w6, w7, w8, w9, w10, w11, w12, w13, w14, w15;
  {
    bf16x8_t x0, x1, x2, x3, x4, x5, x6, x7, x8, x9, x10, x11, x12, x13, x14, x15;
    ISSUE_A16(LDG16P, wbp);
    WAITV(0);
    w0 = x0; w1 = x1; w2 = x2; w3 = x3; w4 = x4; w5 = x5; w6 = x6; w7 = x7;
    w8 = x8; w9 = x9; w10 = x10; w11 = x11; w12 = x12; w13 = x13; w14 = x14; w15 = x15;
  }
  const float bU = (role == 1u) ? g_b1[cbase + lrow] : 0.f;
  const unsigned rcOff = (rw + crow4) * 512u + cbase + lrow;  // C/D per-lane base elem
  const f32x4 z4 = {0.f, 0.f, 0.f, 0.f};

  for (unsigned i = 0;; ++i) {
    const unsigned slot = i & 1u;
    const bool act = (role == 0u) ? (i < 1024u)
                   : (role == 1u) ? (i >= 1u && i <= 1024u)
                                  : (i >= 2u && i <= 1025u);
    if (act) {
      unsigned p0, p1, p2, p3;                // role0: pre0 bf16 (zext)
      float u0, u1, u2, u3;                   // role2: U f32
      const unsigned short* aBase;
      if (role == 0u) {
        const unsigned short* pb = g_pre0 + ((size_t)i * 128u + rw + crow4) * 512u + cbase + lrow;
        LDU16(p0, pb, 0); LDU16(p1, pb, 1024); LDU16(p2, pb, 2048); LDU16(p3, pb, 3072);
        aBase = &g_h0[(i + 1u) & 1u][0];      // h0[i-1]
      } else if (role == 1u) {
        aBase = &g_h0[(i + 1u) & 1u][0];      // h0[i-1]
      } else {
        const float* ub = &g_U[slot][rcOff];  // U[i-2]
        const float* ub2 = ub + 1024u;
        LDF32(u0, ub, 0); LDF32(u1, ub, 2048); LDF32(u2, ub2, 0); LDF32(u3, ub2, 2048);
        aBase = &g_h1[(i + 1u) & 1u][0];      // h1[i-3]
      }
      const unsigned short* ab = aBase + (rw + lrow) * 512u + lko;
      bf16x8_t x0, x1, x2, x3, x4, x5, x6, x7, x8, x9, x10, x11, x12, x13, x14, x15;
      ISSUE_A16(LDG16, ab);
      f32x4 accA = z4, accB = z4;             // two independent MFMA dep-chains
      WAITV(12);
      accA = MF(x0, w0, accA); accB = MF(x1, w1, accB);
      accA = MF(x2, w2, accA); accB = MF(x3, w3, accB);
      WAITV(8);
      accA = MF(x4, w4, accA); accB = MF(x5, w5, accB);
      accA = MF(x6, w6, accA); accB = MF(x7, w7, accB);
      WAITV(4);
      accA = MF(x8, w8, accA); accB = MF(x9, w9, accB);
      accA = MF(x10, w10, accA); accB = MF(x11, w11, accB);
      WAITV(0);
      accA = MF(x12, w12, accA); accB = MF(x13, w13, accB);
      accA = MF(x14, w14, accA); accB = MF(x15, w15, accB);
      f32x4 s = accA + accB;
      if (role == 0u) {                       // h0[i] = tanh(s + pre0[i])
        unsigned short* hob = &g_h0[slot][rcOff];
        unsigned o0 = f2bf(tanh_fast(s[0] + bf2f((unsigned short)p0)));
        unsigned o1 = f2bf(tanh_fast(s[1] + bf2f((unsigned short)p1)));
        unsigned o2 = f2bf(tanh_fast(s[2] + bf2f((unsigned short)p2)));
        unsigned o3 = f2bf(tanh_fast(s[3] + bf2f((unsigned short)p3)));
        ST2(hob, 0, o0); ST2(hob, 1024, o1); ST2(hob, 2048, o2); ST2(hob, 3072, o3);
      } else if (role == 1u) {                // U[i-1] = s + b1
        float* uob = &g_U[(i - 1u) & 1u][rcOff];
        float* uob2 = uob + 1024u;
        float v0 = s[0] + bU, v1 = s[1] + bU, v2 = s[2] + bU, v3 = s[3] + bU;
        STF(uob, 0, v0); STF(uob, 2048, v1); STF(uob2, 0, v2); STF(uob2, 2048, v3);
      } else {                                // h1[i-2] = tanh(s + U[i-2])
        unsigned short* hob = &g_h1[slot][rcOff];
        unsigned o0 = f2bf(tanh_fast(s[0] + u0));
        unsigned o1 = f2bf(tanh_fast(s[1] + u1));
        unsigned o2 = f2bf(tanh_fast(s[2] + u2));
        unsigned o3 = f2bf(tanh_fast(s[3] + u3));
        ST2(hob, 0, o0); ST2(hob, 1024, o1); ST2(hob, 2048, o2); ST2(hob, 3072, o3);
      }
    }
    if (i == 1025u) { WAITV(0); break; }      // drain final stores; fc sees h1[1023]

    // ---- all-to-all flag barrier ----
    WAITV(0);                                 // drain this wave's sc1 stores (asm-invisible to compiler)
    __syncthreads();
    if (tid == 0u)
      __hip_atomic_store(&g_flag[wg], i + 1u, __ATOMIC_RELAXED, __HIP_MEMORY_SCOPE_AGENT);
    if (w == 0u) {
      while (__hip_atomic_load(&g_flag[lane], __ATOMIC_RELAXED, __HIP_MEMORY_SCOPE_AGENT) < i + 1u) {}
    } else if (w == 1u && lane < 32u) {
      while (__hip_atomic_load(&g_flag[64u + lane], __ATOMIC_RELAXED, __HIP_MEMORY_SCOPE_AGENT) < i + 1u) {}
    }
    __syncthreads();
  }
}

// ---------------------------------------------------------------- fc: h1_final @ fc_w^T + fc_b
__global__ __launch_bounds__(256) void fc_kernel(const float* __restrict__ fc_w,
                                                 const float* __restrict__ fc_b,
                                                 float* __restrict__ out) {
  const unsigned wg = blockIdx.x;
  const unsigned lane = threadIdx.x & 63u, w = threadIdx.x >> 6;
  const unsigned lrow = lane & 15u, lko = (lane >> 4) * 8u, crow = (lane >> 4) * 4u;
  const unsigned n0 = wg * 64u + w * 16u;
  const unsigned short* __restrict__ h1 = &g_h1[1][0];   // slot(1023)
  f32x4 z4 = {0.f, 0.f, 0.f, 0.f};
  f32x4 acc[8];
#pragma unroll
  for (int a = 0; a < 8; ++a) acc[a] = z4;
  const unsigned n = n0 + lrow;
  for (unsigned kk = 0; kk < 16u; ++kk) {
    unsigned k0 = kk * 32u + lko;
    bf16x8_t bfr = {0, 0, 0, 0, 0, 0, 0, 0};
    if (n < 1000u) bfr = cvt8f(fc_w + n * 512u + k0);
#pragma unroll
    for (unsigned mi = 0; mi < 8u; ++mi) {
      bf16x8_t afr = *(const bf16x8_t*)(h1 + (mi * 16u + lrow) * 512u + k0);
      acc[mi] = MF(afr, bfr, acc[mi]);
    }
  }
#pragma unroll
  for (unsigned mi = 0; mi < 8u; ++mi)
#pragma unroll
    for (unsigned r = 0; r < 4u; ++r) {
      unsigned row = mi * 16u + crow + r;
      unsigned col = n0 + lrow;
      if (col < 1000u) out[row * 1000u + col] = acc[mi][r] + fc_b[col];
    }
}

// ---------------------------------------------------------------- launch
extern "C" void kernel_launch(void* const* d_in, const int* in_sizes, int n_in,
                              void* d_out, int out_size, void* d_ws, size_t ws_size,
                              hipStream_t stream) {
  (void)in_sizes; (void)n_in; (void)out_size; (void)d_ws; (void)ws_size;
  const float* x     = (const float*)d_in[0];
  const float* Wx0_w = (const float*)d_in[1];
  const float* Wx0_b = (const float*)d_in[2];
  const float* Wh0_w = (const float*)d_in[3];
  const float* Wh0_b = (const float*)d_in[4];
  const float* Wx1_w = (const float*)d_in[5];
  const float* Wx1_b = (const float*)d_in[6];
  const float* Wh1_w = (const float*)d_in[7];
  const float* Wh1_b = (const float*)d_in[8];
  const float* fc_w  = (const float*)d_in[9];
  const float* fc_b  = (const float*)d_in[10];

  prep_kernel<<<1024, 256, 0, stream>>>(Wh0_w, Wx1_w, Wh1_w, Wx1_b, Wh1_b);
  pre0_kernel<<<1024, 512, 0, stream>>>(x, Wx0_w, Wx0_b, Wh0_b);
  rnn_kernel<<<NWG, 512, 0, stream>>>();
  fc_kernel<<<16, 256, 0, stream>>>(fc_w, fc_b, (float*)d_out);
}

// Round 9
// 7028.542 us; speedup vs baseline: 5.1555x; 1.1603x over previous
//
#include <hip/hip_runtime.h>

// MultiLayerRNN: B=128, T=1024, D_IN=256, H=512, C=1000
// Round 9: round-8 chain protocol (full-history, no WAR) re-expressed in
// ONLY validated idioms:
//   - data loads/stores: "off"-form asm with 64-bit per-lane vaddr (r4/r5)
//   - flags: __hip_atomic_load/store RELAXED AGENT (r2-r5)
//   - pre0: plain C++ loads (r2-r5)
//   - reduced VGPR pressure (~235): no saddr asm, no prefetch state machines
// 8 chains x {L0A,L0B,UA,UB,CA,CB} = 48 WGs x 512 thr. Zero LDS in hot loop.

typedef __attribute__((ext_vector_type(8))) short bf16x8_t;
typedef __attribute__((ext_vector_type(4))) float f32x4;
typedef unsigned long long u64;

#define NCH 8u
#define SPIN_CAP (1u << 17)

__device__ __align__(16) unsigned short g_W[3][512 * 512];   // bf16 [n][k]: Wh0, Wx1, Wh1
__device__ float g_b1[512];
__device__ __align__(16) unsigned short g_pre0T[1024u * 512u * 128u]; // bf16 [t][c][128r]
__device__ __align__(16) unsigned short g_h0H[NCH][1025][8192];       // slot s = h0[s-1], [16r][512c]
__device__ __align__(16) unsigned short g_h1H[NCH][1025][8192];       // slot s = h1[s-1]
__device__ __align__(16) float g_UH[NCH][1024][8192];                 // [t][512c][16r] f32
__device__ __align__(16) unsigned g_prog[NCH * 8];

__device__ __forceinline__ unsigned short f2bf(float f) {
  unsigned u = __float_as_uint(f);
  u += 0x7fffu + ((u >> 16) & 1u);   // RNE
  return (unsigned short)(u >> 16);
}
__device__ __forceinline__ float bf2f(unsigned short h) {
  return __uint_as_float(((unsigned)h) << 16);
}
__device__ __forceinline__ bf16x8_t cvt8f(const float* p) {
  bf16x8_t r;
#pragma unroll
  for (int i = 0; i < 8; ++i) r[i] = (short)f2bf(p[i]);
  return r;
}
__device__ __forceinline__ float tanh_fast(float x) {
  float e = __expf(2.f * x);
  return 1.f - 2.f / (e + 1.f);
}

#define MF(a, b, c) __builtin_amdgcn_mfma_f32_16x16x32_bf16(a, b, c, 0, 0, 0)
#define WAITV0 do { asm volatile("s_waitcnt vmcnt(0)" ::: "memory"); __builtin_amdgcn_sched_barrier(0); } while (0)

// validated r4/r5 patterns: 64-bit per-lane vaddr ("off" form), sc1 = IC-coherent
#define LDG16(dst, base, OFF) \
  asm volatile("global_load_dwordx4 %0, %1, off offset:" #OFF " sc1" : "=v"(dst) : "v"(base))
#define LDF4(dst, base, OFF) \
  asm volatile("global_load_dwordx4 %0, %1, off offset:" #OFF " sc1" : "=v"(dst) : "v"(base))
#define ST2(base, OFF, val) \
  asm volatile("global_store_short %0, %1, off offset:" #OFF " sc1" :: "v"(base), "v"(val))
#define STF4(base, OFF, val) \
  asm volatile("global_store_dwordx4 %0, %1, off offset:" #OFF " sc1" :: "v"(base), "v"(val))

__device__ __forceinline__ unsigned aload(const unsigned* p) {
  return __hip_atomic_load(p, __ATOMIC_RELAXED, __HIP_MEMORY_SCOPE_AGENT);
}
__device__ __forceinline__ void spin_ge(const unsigned* p, unsigned tgt) {
  unsigned sp = 0;
  while (aload(p) < tgt && ++sp < SPIN_CAP) {}
}

// ---------------------------------------------------------------- prep
__global__ void prep_kernel(const float* __restrict__ Wh0_w, const float* __restrict__ Wx1_w,
                            const float* __restrict__ Wh1_w, const float* __restrict__ Wx1_b,
                            const float* __restrict__ Wh1_b) {
  size_t tid = (size_t)blockIdx.x * blockDim.x + threadIdx.x;
  size_t stride = (size_t)gridDim.x * blockDim.x;
  for (size_t i = tid; i < 512u * 512u; i += stride) {
    g_W[0][i] = f2bf(Wh0_w[i]);
    g_W[1][i] = f2bf(Wx1_w[i]);
    g_W[2][i] = f2bf(Wh1_w[i]);
  }
  for (size_t i = tid; i < 512u; i += stride) g_b1[i] = Wx1_b[i] + Wh1_b[i];
  for (size_t i = tid; i < NCH * 8u; i += stride) g_prog[i] = 0u;
  // zero ALL history: unlicensed reads -> 0.0, never garbage
  uint4 z = {0u, 0u, 0u, 0u};
  uint4* p0 = (uint4*)&g_h0H[0][0][0];
  uint4* p1 = (uint4*)&g_h1H[0][0][0];
  size_t nh = sizeof(g_h0H) / 16u;
  for (size_t i = tid; i < nh; i += stride) { p0[i] = z; p1[i] = z; }
  uint4* pu = (uint4*)&g_UH[0][0][0];
  size_t nu = sizeof(g_UH) / 16u;
  for (size_t i = tid; i < nu; i += stride) pu[i] = z;
}

// ---------------------------------------------------------------- pre0: x @ Wx0^T + biases -> [t][c][128r]
__global__ __launch_bounds__(512) void pre0_kernel(const float* __restrict__ x,
                                                   const float* __restrict__ Wx0_w,
                                                   const float* __restrict__ Wx0_b,
                                                   const float* __restrict__ Wh0_b) {
  const unsigned t = blockIdx.x;
  const unsigned lane = threadIdx.x & 63u, w = threadIdx.x >> 6;
  const unsigned lrow = lane & 15u, lko = (lane >> 4) * 8u, crow = (lane >> 4) * 4u;
  const unsigned ncol0 = w * 64u;
  f32x4 z4 = {0.f, 0.f, 0.f, 0.f};
  f32x4 acc[8][4];
#pragma unroll
  for (int a = 0; a < 8; ++a)
#pragma unroll
    for (int b = 0; b < 4; ++b) acc[a][b] = z4;

  for (unsigned kk = 0; kk < 8u; ++kk) {
    unsigned k0 = kk * 32u + lko;
    bf16x8_t bfr[4];
#pragma unroll
    for (unsigned nj = 0; nj < 4u; ++nj) {
      unsigned n = ncol0 + nj * 16u + lrow;
      bfr[nj] = cvt8f(Wx0_w + n * 256u + k0);
    }
#pragma unroll
    for (unsigned mi = 0; mi < 8u; ++mi) {
      unsigned m = mi * 16u + lrow;
      bf16x8_t afr = cvt8f(x + ((size_t)m * 1024u + t) * 256u + k0);
#pragma unroll
      for (unsigned nj = 0; nj < 4u; ++nj)
        acc[mi][nj] = MF(afr, bfr[nj], acc[mi][nj]);
    }
  }
#pragma unroll
  for (unsigned mi = 0; mi < 8u; ++mi)
#pragma unroll
    for (unsigned nj = 0; nj < 4u; ++nj) {
      unsigned col = ncol0 + nj * 16u + lrow;
      u64 pv = 0ull;
#pragma unroll
      for (unsigned r = 0; r < 4u; ++r) {
        float v = acc[mi][nj][r] + Wx0_b[col] + Wh0_b[col];
        pv |= ((u64)f2bf(v)) << (16u * r);
      }
      *(u64*)(&g_pre0T[((size_t)t * 512u + col) * 128u + mi * 16u + crow]) = pv;
    }
}

// ---------------------------------------------------------------- per-role persistent loop
// STAGE: 0 = L0 (h0 self-loop + pre0), 1 = U (U = h0@Wx1^T + b1), 2 = C (h1 self-loop + U)
template<int STAGE>
__device__ __forceinline__ void run_role(unsigned ch, unsigned hh) {
  const unsigned tid = threadIdx.x;
  const unsigned lane = tid & 63u, w = tid >> 6;
  const unsigned lrow = lane & 15u, kq = (lane >> 4) * 8u, crow4 = (lane >> 4) * 4u;
  const unsigned n0 = hh * 256u + w * 32u + lrow;      // wave's output col (per lane)

  // ---- B weights -> VGPRs once; frag f<8 = own k-half, f>=8 = sibling k-half ----
  bf16x8_t wB0[16], wB1[16];
  {
    const unsigned short* wp = g_W[STAGE];
#pragma unroll
    for (int f = 0; f < 16; ++f) {
      unsigned kfl = (STAGE == 1) ? (unsigned)f
                                  : ((f < 8) ? hh * 8u + (unsigned)f : (1u - hh) * 8u + (unsigned)(f - 8));
      wB0[f] = *(const bf16x8_t*)(wp + ((size_t)n0 * 512u + kfl * 32u + kq));
      wB1[f] = *(const bf16x8_t*)(wp + ((size_t)(n0 + 16u) * 512u + kfl * 32u + kq));
    }
  }
  float bu0 = 0.f, bu1 = 0.f;
  if (STAGE == 1) { bu0 = g_b1[n0]; bu1 = g_b1[n0 + 16u]; }

  // ---- uniform bases ----
  const unsigned short* aB = (STAGE == 2) ? &g_h1H[ch][0][0] : &g_h0H[ch][0][0];
  unsigned short* oB = (STAGE == 0) ? &g_h0H[ch][0][0] : &g_h1H[ch][0][0];
  unsigned* prog = &g_prog[ch * 8u];
  unsigned* myProg = &prog[STAGE * 2u + hh];
  const unsigned* pSib = &prog[STAGE * 2u + (1u - hh)];
  const unsigned* pUsrc = &prog[2u + hh];
  const unsigned* pL0A = &prog[0];
  const unsigned* pL0B = &prog[1];

  const f32x4 z4 = {0.f, 0.f, 0.f, 0.f};

  for (unsigned t = 0; t < 1024u; ++t) {
    bf16x8_t x0, x1, x2, x3, x4, x5, x6, x7, x8, x9, x10, x11, x12, x13, x14, x15;
    f32x4 acc0 = z4, acc1 = z4;
    f32x4 u0 = z4, u1 = z4;
    u64 p0a = 0ull, p0b = 0ull;

    if (STAGE == 0) {
      // plain cached loads (written by earlier kernel); compiler waits at use (epilogue)
      const unsigned short* pp = g_pre0T + ((size_t)t * 512u + n0) * 128u + ch * 16u + crow4;
      p0a = *(const u64*)pp;
      p0b = *(const u64*)(pp + 2048u);                    // +16 cols
    }

    if (STAGE != 1) {
      // ---- self-loop: A = h[t-1] = slot t. own half by program order (posted
      //      flag t implies own stores drained); sibling half licensed by flag >= t ----
      const unsigned short* pA = aB + (size_t)t * 8192u + lrow * 512u + kq;
      const unsigned short* pOwn = pA + hh * 256u;
      const unsigned short* pSb = pA + (1u - hh) * 256u;
      LDG16(x0, pOwn, 0);   LDG16(x1, pOwn, 64);  LDG16(x2, pOwn, 128); LDG16(x3, pOwn, 192);
      LDG16(x4, pOwn, 256); LDG16(x5, pOwn, 320); LDG16(x6, pOwn, 384); LDG16(x7, pOwn, 448);
      spin_ge(pSib, t);
      LDG16(x8, pSb, 0);    LDG16(x9, pSb, 64);  LDG16(x10, pSb, 128); LDG16(x11, pSb, 192);
      LDG16(x12, pSb, 256); LDG16(x13, pSb, 320); LDG16(x14, pSb, 384); LDG16(x15, pSb, 448);
      if (STAGE == 2) {
        spin_ge(pUsrc, t + 1u);                           // U[t] ready
        const float* pU = &g_UH[ch][t][0] + (size_t)n0 * 16u + crow4;
        LDF4(u0, pU, 0); LDF4(u1, pU, 1024);              // cols n0, n0+16
      }
    } else {
      // ---- U: A = h0[t] = slot t+1, licensed by both L0 flags >= t+1 ----
      spin_ge(pL0A, t + 1u);
      spin_ge(pL0B, t + 1u);
      const unsigned short* pA = aB + (size_t)(t + 1u) * 8192u + lrow * 512u + kq;
      LDG16(x0, pA, 0);    LDG16(x1, pA, 64);  LDG16(x2, pA, 128);  LDG16(x3, pA, 192);
      LDG16(x4, pA, 256);  LDG16(x5, pA, 320); LDG16(x6, pA, 384);  LDG16(x7, pA, 448);
      LDG16(x8, pA, 512);  LDG16(x9, pA, 576); LDG16(x10, pA, 640); LDG16(x11, pA, 704);
      LDG16(x12, pA, 768); LDG16(x13, pA, 832); LDG16(x14, pA, 896); LDG16(x15, pA, 960);
    }

    WAITV0;                                               // all A (+U) landed
#define MM(F) do { acc0 = MF(x##F, wB0[F], acc0); acc1 = MF(x##F, wB1[F], acc1); } while (0)
    MM(0); MM(1); MM(2); MM(3); MM(4); MM(5); MM(6); MM(7);
    MM(8); MM(9); MM(10); MM(11); MM(12); MM(13); MM(14); MM(15);
#undef MM

    if (STAGE == 1) {
      float* uo = &g_UH[ch][t][0] + (size_t)n0 * 16u + crow4;
      f32x4 o0, o1;
#pragma unroll
      for (int j = 0; j < 4; ++j) { o0[j] = acc0[j] + bu0; o1[j] = acc1[j] + bu1; }
      STF4(uo, 0, o0); STF4(uo, 1024, o1);                // virgin slot: no WAR
    } else {
      unsigned short* ho = oB + (size_t)(t + 1u) * 8192u + crow4 * 512u + n0;
      float e0, e1, e2, e3, f0, f1, f2, f3;
      if (STAGE == 0) {
        e0 = bf2f((unsigned short)(p0a));        e1 = bf2f((unsigned short)(p0a >> 16));
        e2 = bf2f((unsigned short)(p0a >> 32));  e3 = bf2f((unsigned short)(p0a >> 48));
        f0 = bf2f((unsigned short)(p0b));        f1 = bf2f((unsigned short)(p0b >> 16));
        f2 = bf2f((unsigned short)(p0b >> 32));  f3 = bf2f((unsigned short)(p0b >> 48));
      } else {
        e0 = u0[0]; e1 = u0[1]; e2 = u0[2]; e3 = u0[3];
        f0 = u1[0]; f1 = u1[1]; f2 = u1[2]; f3 = u1[3];
      }
      unsigned o;
      o = f2bf(tanh_fast(acc0[0] + e0)); ST2(ho, 0, o);
      o = f2bf(tanh_fast(acc0[1] + e1)); ST2(ho, 1024, o);
      o = f2bf(tanh_fast(acc0[2] + e2)); ST2(ho, 2048, o);
      o = f2bf(tanh_fast(acc0[3] + e3)); ST2(ho, 3072, o);
      o = f2bf(tanh_fast(acc1[0] + f0)); ST2(ho, 32, o);
      o = f2bf(tanh_fast(acc1[1] + f1)); ST2(ho, 1056, o);
      o = f2bf(tanh_fast(acc1[2] + f2)); ST2(ho, 2080, o);
      o = f2bf(tanh_fast(acc1[3] + f3)); ST2(ho, 3104, o);
    }

    // ---- post progress: per-wave drain -> WG barrier -> tid0 posts flag ----
    WAITV0;
    __syncthreads();
    if (tid == 0u)
      __hip_atomic_store(myProg, t + 1u, __ATOMIC_RELAXED, __HIP_MEMORY_SCOPE_AGENT);
  }
}

// ---------------------------------------------------------------- persistent recurrence
__global__ __launch_bounds__(512, 1) void rnn_kernel() {
  const unsigned wg = blockIdx.x;
  const unsigned ch = wg / 6u;
  const unsigned r = wg % 6u;
  const unsigned stage = r >> 1, hh = r & 1u;
  if (stage == 0u) run_role<0>(ch, hh);
  else if (stage == 1u) run_role<1>(ch, hh);
  else run_role<2>(ch, hh);
}

// ---------------------------------------------------------------- fc: h1_final @ fc_w^T + fc_b
__global__ __launch_bounds__(256) void fc_kernel(const float* __restrict__ fc_w,
                                                 const float* __restrict__ fc_b,
                                                 float* __restrict__ out) {
  const unsigned wg = blockIdx.x;
  const unsigned lane = threadIdx.x & 63u, w = threadIdx.x >> 6;
  const unsigned lrow = lane & 15u, lko = (lane >> 4) * 8u, crow = (lane >> 4) * 4u;
  const unsigned n0 = wg * 64u + w * 16u;
  f32x4 z4 = {0.f, 0.f, 0.f, 0.f};
  f32x4 acc[8];
#pragma unroll
  for (int a = 0; a < 8; ++a) acc[a] = z4;
  const unsigned n = n0 + lrow;
  for (unsigned kk = 0; kk < 16u; ++kk) {
    unsigned k0 = kk * 32u + lko;
    bf16x8_t bfr = {0, 0, 0, 0, 0, 0, 0, 0};
    if (n < 1000u) bfr = cvt8f(fc_w + n * 512u + k0);
#pragma unroll
    for (unsigned mi = 0; mi < 8u; ++mi) {
      bf16x8_t afr = *(const bf16x8_t*)(&g_h1H[mi][1024][lrow * 512u + k0]);  // h1[1023], chain mi
      acc[mi] = MF(afr, bfr, acc[mi]);
    }
  }
#pragma unroll
  for (unsigned mi = 0; mi < 8u; ++mi)
#pragma unroll
    for (unsigned rr = 0; rr < 4u; ++rr) {
      unsigned row = mi * 16u + crow + rr;
      unsigned col = n0 + lrow;
      if (col < 1000u) out[row * 1000u + col] = acc[mi][rr] + fc_b[col];
    }
}

// ---------------------------------------------------------------- launch
extern "C" void kernel_launch(void* const* d_in, const int* in_sizes, int n_in,
                              void* d_out, int out_size, void* d_ws, size_t ws_size,
                              hipStream_t stream) {
  (void)in_sizes; (void)n_in; (void)out_size; (void)d_ws; (void)ws_size;
  const float* x     = (const float*)d_in[0];
  const float* Wx0_w = (const float*)d_in[1];
  const float* Wx0_b = (const float*)d_in[2];
  const float* Wh0_w = (const float*)d_in[3];
  const float* Wh0_b = (const float*)d_in[4];
  const float* Wx1_w = (const float*)d_in[5];
  const float* Wx1_b = (const float*)d_in[6];
  const float* Wh1_w = (const float*)d_in[7];
  const float* Wh1_b = (const float*)d_in[8];
  const float* fc_w  = (const float*)d_in[9];
  const float* fc_b  = (const float*)d_in[10];

  prep_kernel<<<1024, 256, 0, stream>>>(Wh0_w, Wx1_w, Wh1_w, Wx1_b, Wh1_b);
  pre0_kernel<<<1024, 512, 0, stream>>>(x, Wx0_w, Wx0_b, Wh0_b);
  rnn_kernel<<<48, 512, 0, stream>>>();
  fc_kernel<<<16, 256, 0, stream>>>(fc_w, fc_b, (float*)d_out);
}